// Round 4
// baseline (981.366 us; speedup 1.0000x reference)
//
#include <hip/hip_runtime.h>
#include <hip/hip_cooperative_groups.h>
namespace cg = cooperative_groups;

#define NN 3072
#define FIN 1546
#define KP 1568          // FIN padded to multiple of 32
#define MAXR 192         // max CSR nnz/row (measured mean ~61)

#define XS4_BLOCKS (NN * KP / 1024)        // 4704  (4 elems/thread)
#define WSPLIT_BLOCKS (256 * KP / 256)     // 1568
#define WG_BLOCKS 704                       // 384 WgaT + 192 WgbT + 128 WaT
#define CSR_BLOCKS (NN / 4)                // 768
#define PREP_UNITS (XS4_BLOCKS + WSPLIT_BLOCKS + WG_BLOCKS + CSR_BLOCKS)  // 7744
#define FC1_UNITS (NN / 16 * 4)            // 768: 192 row-tiles x 4 col-tiles
#define P1_UNITS (FC1_UNITS + 3 * NN)      // 9984

typedef __attribute__((ext_vector_type(8))) __bf16 bf16x8;
typedef __attribute__((ext_vector_type(4))) __bf16 bf16x4;
typedef __attribute__((ext_vector_type(4))) float f32x4;

struct MegaArgs {
    // inputs
    const float *adj, *X, *Wfc1, *bfc1, *thr;
    const float *Wga0, *Wga1, *Wga2, *Wgb0, *Wgb1, *Wgb2, *Wa;
    const float *bga0, *bga1, *bga2, *bgb0, *bgb1, *bgb2;
    const float *cnnk, *cnnb, *ba, *Wb, *bb;
    const int *left, *right;
    // workspace
    int *cols; float *vals; int *cnt; float *dvec;
    int *mcols; float *mvals; int *mcnt; float *db;
    __bf16 *Xh, *Xl, *WhT, *WlT;
    __bf16 *WgaTh, *WgaTl, *WgbTh, *WgbTl, *WaTh, *WaTl;
    __bf16 *X0h, *X0l;
    float *XWall; __bf16 *e1h, *e1l; float *HW2all; float *embf;
    __bf16 *embh, *embl; float *uvp;
    // outputs
    float *out_logits, *out_emb;
};

// ---- phase 0 unit: xsplit x4 ; wsplit ; Wg/Wa transpose+split ; csr build ----
__device__ __forceinline__ void prep_unit(const MegaArgs& A, int bid, int tid) {
    if (bid < XS4_BLOCKS) {
        int e = (bid * 256 + tid) * 4;                // 4 elems, same row (KP%4==0)
        int i = e / KP, c = e - i * KP;
        const float* xr = A.X + (size_t)i * FIN + c;
        float x0 = (c + 0 < FIN) ? xr[0] : 0.f;
        float x1 = (c + 1 < FIN) ? xr[1] : 0.f;
        float x2 = (c + 2 < FIN) ? xr[2] : 0.f;
        float x3 = (c + 3 < FIN) ? xr[3] : 0.f;
        __bf16 h0 = (__bf16)x0, h1 = (__bf16)x1, h2 = (__bf16)x2, h3 = (__bf16)x3;
        bf16x4 hv = {h0, h1, h2, h3};
        bf16x4 lv = {(__bf16)(x0 - (float)h0), (__bf16)(x1 - (float)h1),
                     (__bf16)(x2 - (float)h2), (__bf16)(x3 - (float)h3)};
        *(bf16x4*)(A.Xh + e) = hv;
        *(bf16x4*)(A.Xl + e) = lv;
        return;
    }
    int b2 = bid - XS4_BLOCKS;
    if (b2 < WSPLIT_BLOCKS) {
        int idx = b2 * 256 + tid;
        int c = idx / KP, k = idx - c * KP;
        float x = (k < FIN) ? A.Wfc1[(size_t)k * 256 + c] : 0.f;
        __bf16 h = (__bf16)x;
        A.WhT[idx] = h;
        A.WlT[idx] = (__bf16)(x - (float)h);
        return;
    }
    b2 -= WSPLIT_BLOCKS;
    if (b2 < WG_BLOCKS) {
        int idx = b2 * 256 + tid;
        float x;
        __bf16 *oh, *ol;
        int off;
        if (idx < 98304) {                      // WgaT[b][c][k]: [3][128][256]
            int b = idx >> 15, r = idx & 32767;
            int c = r >> 8, k = r & 255;
            const float* Wp = (b == 0) ? A.Wga0 : (b == 1) ? A.Wga1 : A.Wga2;
            x = Wp[k * 128 + c];
            oh = A.WgaTh; ol = A.WgaTl; off = idx;
        } else if (idx < 98304 + 49152) {       // WgbT[b][c][k]: [3][128][128]
            int j = idx - 98304;
            int b = j >> 14, r = j & 16383;
            int c = r >> 7, k = r & 127;
            const float* Wp = (b == 0) ? A.Wgb0 : (b == 1) ? A.Wgb1 : A.Wgb2;
            x = Wp[k * 128 + c];
            oh = A.WgbTh; ol = A.WgbTl; off = j;
        } else {                                // WaT[c][k]: [128][256]
            int j = idx - 147456;
            int c = j >> 8, k = j & 255;
            x = (c < 64) ? A.Wa[(size_t)k * 64 + c] : A.Wa[(size_t)(256 + k) * 64 + (c - 64)];
            oh = A.WaTh; ol = A.WaTl; off = j;
        }
        __bf16 h = (__bf16)x;
        oh[off] = h;
        ol[off] = (__bf16)(x - (float)h);
        return;
    }
    b2 -= WG_BLOCKS;
    int i = b2 * 4 + (tid >> 6);
    int lane = tid & 63;
    const float* row = A.adj + (size_t)i * NN;
    unsigned long long below = (1ull << lane) - 1ull;
    float s = 0.f; int count = 0;
    int base = i * MAXR;
    for (int c0 = 0; c0 < NN; c0 += 256) {
        float4 a4 = *(const float4*)(row + c0 + lane * 4);
        float a[4] = {a4.x, a4.y, a4.z, a4.w};
        s += a[0] + a[1] + a[2] + a[3];
        unsigned long long bal[4];
        #pragma unroll
        for (int u = 0; u < 4; u++) bal[u] = __ballot(a[u] != 0.f);
        int before = 0;
        #pragma unroll
        for (int u = 0; u < 4; u++) before += __popcll(bal[u] & below);
        int local = 0;
        #pragma unroll
        for (int u = 0; u < 4; u++) {
            if (a[u] != 0.f) {
                int pos = count + before + local;
                if (pos < MAXR) { A.cols[base + pos] = c0 + lane * 4 + u; A.vals[base + pos] = a[u]; }
                local++;
            }
        }
        int tot = 0;
        #pragma unroll
        for (int u = 0; u < 4; u++) tot += __popcll(bal[u]);
        count += tot;
    }
    for (int off = 32; off; off >>= 1) s += __shfl_xor(s, off);
    if (lane == 0) {
        A.cnt[i] = count < MAXR ? count : MAXR;
        A.dvec[i] = (s > 0.f) ? 1.0f / sqrtf(s) : 0.f;
    }
}

// ---- phase 1a unit: fc1 16x64 tile; wave w owns one 16x16 full-K output ----
__device__ __forceinline__ void fc1_unit(const MegaArgs& A, int u, int tid) {
    int rt = u >> 2;
    int c0 = (u & 3) * 64;
    int w = tid >> 6, lane = tid & 63;
    int m = lane & 15, q = lane >> 4;
    int r0 = rt * 16;
    int cw = c0 + w * 16;
    const __bf16* xh = A.Xh + (size_t)(r0 + m) * KP + q * 8;
    const __bf16* xl = A.Xl + (size_t)(r0 + m) * KP + q * 8;
    const __bf16* bh = A.WhT + (size_t)(cw + m) * KP + q * 8;
    const __bf16* bl = A.WlT + (size_t)(cw + m) * KP + q * 8;

    f32x4 acc;
    #pragma unroll
    for (int r = 0; r < 4; r++) acc[r] = 0.f;

    #pragma unroll 7
    for (int ks = 0; ks < KP; ks += 32) {
        bf16x8 ah = *(const bf16x8*)(xh + ks);
        bf16x8 al = *(const bf16x8*)(xl + ks);
        bf16x8 bhv = *(const bf16x8*)(bh + ks);
        bf16x8 blv = *(const bf16x8*)(bl + ks);
        acc = __builtin_amdgcn_mfma_f32_16x16x32_bf16(ah, bhv, acc, 0, 0, 0);
        acc = __builtin_amdgcn_mfma_f32_16x16x32_bf16(ah, blv, acc, 0, 0, 0);
        acc = __builtin_amdgcn_mfma_f32_16x16x32_bf16(al, bhv, acc, 0, 0, 0);
    }
    int col = cw + m;
    float bv = A.bfc1[col];
    #pragma unroll
    for (int r = 0; r < 4; r++) {
        int row = r0 + q * 4 + r;
        float s = fmaxf(acc[r] + bv, 0.f);
        __bf16 h = (__bf16)s;
        A.X0h[(size_t)row * 256 + col] = h;
        A.X0l[(size_t)row * 256 + col] = (__bf16)(s - (float)h);
    }
}

// ---- phase 1b unit: threshold masks (mode2 An^2 heavy; mode0/1 light) ----
__device__ __forceinline__ void mask_unit(const MegaArgs& A, int t, int tid, char* smem) {
    float* ds    = (float*)smem;           // NN floats (mode2) / 256 floats (mode<2)
    int*   lcols = (int*)(smem + 12288);   // MAXR
    float* lvals = (float*)(smem + 13056); // MAXR
    int*   lcnt  = (int*)(smem + 13824);
    float* osum  = (float*)(smem + 13828);
    int mode, i;
    if (t < NN)          { mode = 2; i = t; }
    else if (t < 2 * NN) { mode = 0; i = t - NN; }
    else                 { mode = 1; i = t - 2 * NN; }

    int* mcols = A.mcols + (size_t)mode * NN * MAXR;
    float* mvals = A.mvals + (size_t)mode * NN * MAXR;
    int* mcnt = A.mcnt + (size_t)mode * NN;
    float* db = A.db + (size_t)mode * NN;
    int ni = A.cnt[i], base = i * MAXR;
    float thr = *A.thr;
    float di = A.dvec[i];

    if (mode < 2) {
        if (tid == 0) *lcnt = 0;
        __syncthreads();
        float s = 0.f;
        if (tid < ni) {
            int j = A.cols[base + tid];
            float a = A.vals[base + tid];
            float mv = (mode == 0) ? a : a * di * A.dvec[j];
            if (mv > thr) {
                int p = atomicAdd(lcnt, 1);
                mcols[base + p] = j;
                mvals[base + p] = a;
                s = a;
            }
        }
        ds[tid] = s; __syncthreads();
        for (int off = 128; off; off >>= 1) {
            if (tid < off) ds[tid] += ds[tid + off];
            __syncthreads();
        }
        if (tid == 0) {
            mcnt[i] = *lcnt;
            db[i] = 1.0f / sqrtf(ds[0] + 1.0f);
        }
        return;
    }

    if (tid == 0) { *osum = 0.f; *lcnt = 0; }
    for (int j = tid; j < NN; j += 256) ds[j] = 0.f;
    __syncthreads();
    for (int t2 = tid; t2 < ni; t2 += 256) {
        int j = A.cols[base + t2];
        float a = A.vals[base + t2];
        lcols[t2] = j; lvals[t2] = a;
        ds[j] = a * A.dvec[j] * A.dvec[j];
    }
    __syncthreads();
    int lane = tid & 63, wv = tid >> 6;
    int sub = lane & 15, dg = lane >> 4;      // 16-lane subgroup, 4 dots/wave in flight
    for (int o = wv * 4 + dg; o < ni; o += 16) {
        int j = lcols[o];
        int nj = A.cnt[j], bj = j * MAXR;
        float dot = 0.f;
        for (int t2 = sub; t2 < nj; t2 += 16)
            dot += A.vals[bj + t2] * ds[A.cols[bj + t2]];
        #pragma unroll
        for (int off = 8; off; off >>= 1) dot += __shfl_xor(dot, off);
        if (sub == 0 && di * A.dvec[j] * dot > thr) {
            int p = atomicAdd(lcnt, 1);
            mcols[base + p] = j;
            mvals[base + p] = lvals[o];
            atomicAdd(osum, lvals[o]);
        }
    }
    __syncthreads();
    if (tid == 0) {
        mcnt[i] = *lcnt;
        db[i] = 1.0f / sqrtf(*osum + 1.0f);
    }
}

// ---- dense MFMA GEMM unit (split-bf16): 64x64 tile, 4 waves ----
__device__ __forceinline__ void gemm_unit(const __bf16* __restrict__ Ah,
                                          const __bf16* __restrict__ Al,
                                          int aplane, int K,
                                          const __bf16* __restrict__ Bh,
                                          const __bf16* __restrict__ Bl,
                                          float* __restrict__ out,
                                          int bx, int by, int bz, int tid) {
    int w = tid >> 6, lane = tid & 63;
    int m = lane & 15, q = lane >> 4;
    int i0 = bx * 64, c0 = by * 64;
    int rowA = i0 + w * 16 + m;
    const __bf16* ah = Ah + (size_t)bz * aplane + (size_t)rowA * K + q * 8;
    const __bf16* al = Al + (size_t)bz * aplane + (size_t)rowA * K + q * 8;
    const __bf16* bh0 = Bh + (size_t)bz * 128 * K + (size_t)(c0 + m) * K + q * 8;
    const __bf16* bl0 = Bl + (size_t)bz * 128 * K + (size_t)(c0 + m) * K + q * 8;

    f32x4 acc[4];
    #pragma unroll
    for (int ct = 0; ct < 4; ct++)
        #pragma unroll
        for (int r = 0; r < 4; r++) acc[ct][r] = 0.f;

    for (int ks = 0; ks < K; ks += 32) {
        bf16x8 a_h = *(const bf16x8*)(ah + ks);
        bf16x8 a_l = *(const bf16x8*)(al + ks);
        #pragma unroll
        for (int ct = 0; ct < 4; ct++) {
            bf16x8 b_h = *(const bf16x8*)(bh0 + (size_t)ct * 16 * K + ks);
            bf16x8 b_l = *(const bf16x8*)(bl0 + (size_t)ct * 16 * K + ks);
            acc[ct] = __builtin_amdgcn_mfma_f32_16x16x32_bf16(a_h, b_h, acc[ct], 0, 0, 0);
            acc[ct] = __builtin_amdgcn_mfma_f32_16x16x32_bf16(a_h, b_l, acc[ct], 0, 0, 0);
            acc[ct] = __builtin_amdgcn_mfma_f32_16x16x32_bf16(a_l, b_h, acc[ct], 0, 0, 0);
        }
    }
    float* outp = out + (size_t)bz * NN * 128;
    int rowBase = i0 + w * 16 + q * 4;
    #pragma unroll
    for (int ct = 0; ct < 4; ct++) {
        int col = c0 + ct * 16 + m;
        #pragma unroll
        for (int r = 0; r < 4; r++)
            outp[(size_t)(rowBase + r) * 128 + col] = acc[ct][r];
    }
}

// ---- SpMM unit: masked CSR, float4 gather, 8-way t-parallel, 2-deep ILP ----
__device__ __forceinline__ void spmm_unit(const MegaArgs& A, int b, int i,
                                          const float* __restrict__ Xin,
                                          const float* __restrict__ bias0,
                                          const float* __restrict__ bias1,
                                          const float* __restrict__ bias2,
                                          __bf16* __restrict__ outAh,
                                          __bf16* __restrict__ outAl,
                                          int coff, int tid, char* smem) {
    float* lcoef = (float*)smem;             // MAXR
    int*   lj    = (int*)(smem + 768);       // MAXR
    float4* part = (float4*)(smem + 1536);   // [8][32]
    const int* mcols = A.mcols + (size_t)b * NN * MAXR;
    const float* mvals = A.mvals + (size_t)b * NN * MAXR;
    const int* mcnt = A.mcnt + (size_t)b * NN;
    const float* db = A.db + (size_t)b * NN;
    const float* Xb = Xin + (size_t)b * NN * 128;
    const float* bias = (b == 0) ? bias0 : (b == 1) ? bias1 : bias2;
    float dbi = db[i];
    int n = mcnt[i], base = i * MAXR;
    if (tid < n) {
        int j = mcols[base + tid];
        lj[tid] = j;
        lcoef[tid] = mvals[base + tid] * dbi * db[j];
    }
    __syncthreads();
    int g = tid >> 5, c4 = (tid & 31) << 2;
    float4 acc = make_float4(0.f, 0.f, 0.f, 0.f);
    float4 acc2 = make_float4(0.f, 0.f, 0.f, 0.f);
    if (g == 0) {
        float4 x = *(const float4*)&Xb[(size_t)i * 128 + c4];
        float d2 = dbi * dbi;
        acc = make_float4(d2 * x.x, d2 * x.y, d2 * x.z, d2 * x.w);
    }
    int t = g;
    for (; t + 8 < n; t += 16) {
        float cf0 = lcoef[t];
        float4 x0 = *(const float4*)&Xb[(size_t)lj[t] * 128 + c4];
        float cf1 = lcoef[t + 8];
        float4 x1 = *(const float4*)&Xb[(size_t)lj[t + 8] * 128 + c4];
        acc.x += cf0 * x0.x; acc.y += cf0 * x0.y; acc.z += cf0 * x0.z; acc.w += cf0 * x0.w;
        acc2.x += cf1 * x1.x; acc2.y += cf1 * x1.y; acc2.z += cf1 * x1.z; acc2.w += cf1 * x1.w;
    }
    if (t < n) {
        float cf = lcoef[t];
        float4 x = *(const float4*)&Xb[(size_t)lj[t] * 128 + c4];
        acc.x += cf * x.x; acc.y += cf * x.y; acc.z += cf * x.z; acc.w += cf * x.w;
    }
    acc.x += acc2.x; acc.y += acc2.y; acc.z += acc2.z; acc.w += acc2.w;
    part[g * 32 + (tid & 31)] = acc;
    __syncthreads();
    if (tid < 32) {
        float4 s = part[tid];
        #pragma unroll
        for (int gg = 1; gg < 8; gg++) {
            float4 t4 = part[gg * 32 + tid];
            s.x += t4.x; s.y += t4.y; s.z += t4.z; s.w += t4.w;
        }
        int cc = tid << 2;
        float4 bv = *(const float4*)&bias[cc];
        s.x = fmaxf(s.x + bv.x, 0.f); s.y = fmaxf(s.y + bv.y, 0.f);
        s.z = fmaxf(s.z + bv.z, 0.f); s.w = fmaxf(s.w + bv.w, 0.f);
        if (outAh) {
            __bf16 h0 = (__bf16)s.x, h1 = (__bf16)s.y, h2 = (__bf16)s.z, h3 = (__bf16)s.w;
            bf16x4 hv = {h0, h1, h2, h3};
            bf16x4 lv = {(__bf16)(s.x - (float)h0), (__bf16)(s.y - (float)h1),
                         (__bf16)(s.z - (float)h2), (__bf16)(s.w - (float)h3)};
            *(bf16x4*)(outAh + ((size_t)b * NN + i) * 128 + cc) = hv;
            *(bf16x4*)(outAl + ((size_t)b * NN + i) * 128 + cc) = lv;
        }
        *(float4*)&A.embf[((size_t)b * NN + i) * 256 + coff + cc] = s;
    }
}

// ---- dilated 3x3 conv unit + split-bf16 emb out ----
__device__ __forceinline__ void conv_unit(const MegaArgs& A, int n, int tid, char* smem) {
    float* rows = (float*)smem;              // [3][3][256]
    int c = tid;
    #pragma unroll
    for (int i = 0; i < 3; i++)
        #pragma unroll
        for (int kh = 0; kh < 3; kh++) {
            int nn2 = n + 2 * kh - 2;
            rows[(i * 3 + kh) * 256 + c] =
                (nn2 >= 0 && nn2 < NN) ? A.embf[((size_t)i * NN + nn2) * 256 + c] : 0.f;
        }
    __syncthreads();
    float s = A.cnnb[0];
    #pragma unroll
    for (int i = 0; i < 3; i++)
        #pragma unroll
        for (int kh = 0; kh < 3; kh++)
            #pragma unroll
            for (int kw = 0; kw < 3; kw++) {
                int cc = c + 2 * kw - 2;
                if (cc >= 0 && cc < 256)
                    s += rows[(i * 3 + kh) * 256 + cc] * A.cnnk[(i * 3 + kh) * 3 + kw];
            }
    size_t idx = (size_t)n * 256 + c;
    A.out_emb[idx] = s;
    __bf16 h = (__bf16)s;
    A.embh[idx] = h;
    A.embl[idx] = (__bf16)(s - (float)h);
}

// ---- uv GEMM unit (MFMA split-bf16, full K=256) ----
__device__ __forceinline__ void uv_unit(const MegaArgs& A, int bx, int by, int tid) {
    int w = tid >> 6, lane = tid & 63;
    int m = lane & 15, q = lane >> 4;
    int i0 = bx * 64, c0 = by * 64;
    int rowA = i0 + w * 16 + m;
    const __bf16* ah = A.embh + (size_t)rowA * 256 + q * 8;
    const __bf16* al = A.embl + (size_t)rowA * 256 + q * 8;
    const __bf16* bh0 = A.WaTh + (size_t)(c0 + m) * 256 + q * 8;
    const __bf16* bl0 = A.WaTl + (size_t)(c0 + m) * 256 + q * 8;

    f32x4 acc[4];
    #pragma unroll
    for (int ct = 0; ct < 4; ct++)
        #pragma unroll
        for (int r = 0; r < 4; r++) acc[ct][r] = 0.f;

    for (int ks = 0; ks < 256; ks += 32) {
        bf16x8 a_h = *(const bf16x8*)(ah + ks);
        bf16x8 a_l = *(const bf16x8*)(al + ks);
        #pragma unroll
        for (int ct = 0; ct < 4; ct++) {
            bf16x8 b_h = *(const bf16x8*)(bh0 + (size_t)ct * 16 * 256 + ks);
            bf16x8 b_l = *(const bf16x8*)(bl0 + (size_t)ct * 16 * 256 + ks);
            acc[ct] = __builtin_amdgcn_mfma_f32_16x16x32_bf16(a_h, b_h, acc[ct], 0, 0, 0);
            acc[ct] = __builtin_amdgcn_mfma_f32_16x16x32_bf16(a_h, b_l, acc[ct], 0, 0, 0);
            acc[ct] = __builtin_amdgcn_mfma_f32_16x16x32_bf16(a_l, b_h, acc[ct], 0, 0, 0);
        }
    }
    int rowBase = i0 + w * 16 + q * 4;
    #pragma unroll
    for (int ct = 0; ct < 4; ct++) {
        int col = c0 + ct * 16 + m;
        #pragma unroll
        for (int r = 0; r < 4; r++)
            A.uvp[(size_t)(rowBase + r) * 128 + col] = acc[ct][r];
    }
}

// ---- pair gather + logits unit: 16 pairs, 4 per wave ----
__device__ __forceinline__ void pair_unit(const MegaArgs& A, int u, int tid) {
    int w = tid >> 6, c = tid & 63;
    int base = u * 16 + w * 4;
    float bac = A.ba[c];
    float w0 = A.Wb[c * 2], w1 = A.Wb[c * 2 + 1];
    float b0 = A.bb[0], b1 = A.bb[1];
    #pragma unroll
    for (int pp = 0; pp < 4; pp++) {
        int row = base + pp;
        int l = A.left[row], r = A.right[row];
        float h = A.uvp[(size_t)l * 128 + c] + A.uvp[(size_t)r * 128 + 64 + c] + bac;
        h = fmaxf(h, 0.f);
        float s0 = h * w0, s1 = h * w1;
        for (int off = 32; off; off >>= 1) {
            s0 += __shfl_xor(s0, off);
            s1 += __shfl_xor(s1, off);
        }
        if (c == 0) {
            A.out_logits[row * 2]     = s0 + b0;
            A.out_logits[row * 2 + 1] = s1 + b1;
        }
    }
}

// ---- the mega kernel: all phases, grid.sync between dependent stages ----
__global__ __launch_bounds__(256, 4) void mega_k(MegaArgs A) {
    cg::grid_group gg = cg::this_grid();
    __shared__ __align__(16) char smem[13856];
    int tid = threadIdx.x;
    int gb = gridDim.x;

    // phase 0: prep (xsplit, wsplit, weight transpose+split, csr build)
    for (int u = blockIdx.x; u < PREP_UNITS; u += gb) prep_unit(A, u, tid);
    gg.sync();

    // phase 1: fc1 (768 tiles) + all threshold masks (9216 units)
    for (int u = blockIdx.x; u < P1_UNITS; u += gb) {
        if (u < FC1_UNITS) fc1_unit(A, u, tid);
        else mask_unit(A, u - FC1_UNITS, tid, smem);
        __syncthreads();   // smem WAR across work-loop iterations
    }
    gg.sync();

    // phase 2: XW[b] = X0 @ Wga[b]
    for (int u = blockIdx.x; u < 288; u += gb) {
        int bx = u % 48, by = (u / 48) & 1, bz = u / 96;
        gemm_unit(A.X0h, A.X0l, 0, 256, A.WgaTh, A.WgaTl, A.XWall, bx, by, bz, tid);
    }
    gg.sync();

    // phase 3: e1[b] = relu(An_b @ XW[b] + bga[b])
    for (int u = blockIdx.x; u < 3 * NN; u += gb) {
        int i = u % NN, b = u / NN;
        spmm_unit(A, b, i, A.XWall, A.bga0, A.bga1, A.bga2, A.e1h, A.e1l, 0, tid, smem);
        __syncthreads();
    }
    gg.sync();

    // phase 4: HW2[b] = e1[b] @ Wgb[b]
    for (int u = blockIdx.x; u < 288; u += gb) {
        int bx = u % 48, by = (u / 48) & 1, bz = u / 96;
        gemm_unit(A.e1h, A.e1l, NN * 128, 128, A.WgbTh, A.WgbTl, A.HW2all, bx, by, bz, tid);
    }
    gg.sync();

    // phase 5: e2[b] = relu(An_b @ HW2[b] + bgb[b])
    for (int u = blockIdx.x; u < 3 * NN; u += gb) {
        int i = u % NN, b = u / NN;
        spmm_unit(A, b, i, A.HW2all, A.bgb0, A.bgb1, A.bgb2, (__bf16*)0, (__bf16*)0, 128, tid, smem);
        __syncthreads();
    }
    gg.sync();

    // phase 6: dilated conv -> out_emb + emb h/l
    for (int u = blockIdx.x; u < NN; u += gb) {
        conv_unit(A, u, tid, smem);
        __syncthreads();
    }
    gg.sync();

    // phase 7: uv = emb_all @ [Wa_left | Wa_right]
    for (int u = blockIdx.x; u < 96; u += gb) {
        int bx = u % 48, by = u / 48;
        uv_unit(A, bx, by, tid);
    }
    gg.sync();

    // phase 8: pair gather + logits
    for (int u = blockIdx.x; u < 1024; u += gb) pair_unit(A, u, tid);
}

extern "C" void kernel_launch(void* const* d_in, const int* in_sizes, int n_in,
                              void* d_out, int out_size, void* d_ws, size_t ws_size,
                              hipStream_t stream) {
    const int* left  = (const int*)d_in[0];
    const int* right = (const int*)d_in[1];
    const float* X    = (const float*)d_in[2];
    const float* adj  = (const float*)d_in[3];
    const float* thr  = (const float*)d_in[4];
    const float* Wfc1 = (const float*)d_in[5];
    const float* bfc1 = (const float*)d_in[6];
    // channel order b0,b1,b2 = (adj mask, Wg5/6), (An mask, Wg3/4), (An^2 mask, Wg1/2)
    const float* Wga[3] = { (const float*)d_in[15], (const float*)d_in[11], (const float*)d_in[7] };
    const float* bga[3] = { (const float*)d_in[16], (const float*)d_in[12], (const float*)d_in[8] };
    const float* Wgb[3] = { (const float*)d_in[17], (const float*)d_in[13], (const float*)d_in[9] };
    const float* bgb[3] = { (const float*)d_in[18], (const float*)d_in[14], (const float*)d_in[10] };
    const float* cnnk = (const float*)d_in[19];
    const float* cnnb = (const float*)d_in[20];
    const float* Wa_  = (const float*)d_in[21];
    const float* ba_  = (const float*)d_in[22];
    const float* Wb_  = (const float*)d_in[23];
    const float* bb_  = (const float*)d_in[24];

    char* p = (char*)d_ws;
    auto take = [&](size_t n) { char* q = p; p += (n + 255) & ~(size_t)255; return q; };
    float* dvec = (float*)take(NN * 4);
    float* db3  = (float*)take((size_t)3 * NN * 4);
    int*   cnt  = (int*)take(NN * 4);
    int*   mcnt3 = (int*)take((size_t)3 * NN * 4);
    int*   cols = (int*)take((size_t)NN * MAXR * 4);
    float* vals = (float*)take((size_t)NN * MAXR * 4);
    int*   mcols3 = (int*)take((size_t)3 * NN * MAXR * 4);    // 7.1 MB
    float* mvals3 = (float*)take((size_t)3 * NN * MAXR * 4);  // 7.1 MB
    __bf16* X0h  = (__bf16*)take((size_t)NN * 256 * 2);
    __bf16* X0l  = (__bf16*)take((size_t)NN * 256 * 2);
    float* XWall = (float*)take((size_t)3 * NN * 128 * 4);
    __bf16* e1h  = (__bf16*)take((size_t)3 * NN * 128 * 2);
    __bf16* e1l  = (__bf16*)take((size_t)3 * NN * 128 * 2);
    float* HW2all= (float*)take((size_t)3 * NN * 128 * 4);
    float* embf  = (float*)take((size_t)3 * NN * 256 * 4);
    __bf16* Xh   = (__bf16*)take((size_t)NN * KP * 2);        // 9.6 MB
    __bf16* Xl   = (__bf16*)take((size_t)NN * KP * 2);        // 9.6 MB
    __bf16* WhT  = (__bf16*)take((size_t)256 * KP * 2);       // 0.8 MB
    __bf16* WlT  = (__bf16*)take((size_t)256 * KP * 2);       // 0.8 MB
    __bf16* WgaTh = (__bf16*)take((size_t)3 * 128 * 256 * 2);
    __bf16* WgaTl = (__bf16*)take((size_t)3 * 128 * 256 * 2);
    __bf16* WgbTh = (__bf16*)take((size_t)3 * 128 * 128 * 2);
    __bf16* WgbTl = (__bf16*)take((size_t)3 * 128 * 128 * 2);
    __bf16* WaTh  = (__bf16*)take((size_t)128 * 256 * 2);
    __bf16* WaTl  = (__bf16*)take((size_t)128 * 256 * 2);
    __bf16* embh  = (__bf16*)take((size_t)NN * 256 * 2);
    __bf16* embl  = (__bf16*)take((size_t)NN * 256 * 2);
    float* uvp   = (float*)take((size_t)NN * 128 * 4);        // 1.5 MB

    float* out_logits = (float*)d_out;
    float* out_emb = out_logits + 32768;

    MegaArgs a;
    a.adj = adj; a.X = X; a.Wfc1 = Wfc1; a.bfc1 = bfc1; a.thr = thr;
    a.Wga0 = Wga[0]; a.Wga1 = Wga[1]; a.Wga2 = Wga[2];
    a.Wgb0 = Wgb[0]; a.Wgb1 = Wgb[1]; a.Wgb2 = Wgb[2]; a.Wa = Wa_;
    a.bga0 = bga[0]; a.bga1 = bga[1]; a.bga2 = bga[2];
    a.bgb0 = bgb[0]; a.bgb1 = bgb[1]; a.bgb2 = bgb[2];
    a.cnnk = cnnk; a.cnnb = cnnb; a.ba = ba_; a.Wb = Wb_; a.bb = bb_;
    a.left = left; a.right = right;
    a.cols = cols; a.vals = vals; a.cnt = cnt; a.dvec = dvec;
    a.mcols = mcols3; a.mvals = mvals3; a.mcnt = mcnt3; a.db = db3;
    a.Xh = Xh; a.Xl = Xl; a.WhT = WhT; a.WlT = WlT;
    a.WgaTh = WgaTh; a.WgaTl = WgaTl; a.WgbTh = WgbTh; a.WgbTl = WgbTl;
    a.WaTh = WaTh; a.WaTl = WaTl;
    a.X0h = X0h; a.X0l = X0l;
    a.XWall = XWall; a.e1h = e1h; a.e1l = e1l; a.HW2all = HW2all; a.embf = embf;
    a.embh = embh; a.embl = embl; a.uvp = uvp;
    a.out_logits = out_logits; a.out_emb = out_emb;

    static int megaGrid = 0;
    if (megaGrid == 0) {
        int occ = 0;
        hipOccupancyMaxActiveBlocksPerMultiprocessor(&occ, mega_k, 256, 0);
        if (occ < 1) occ = 1;
        if (occ > 8) occ = 8;
        megaGrid = occ * 256;
    }

    void* kargs[] = { (void*)&a };
    hipLaunchCooperativeKernel(mega_k, dim3(megaGrid), dim3(256), kargs, 0, stream);
}

// Round 5
// 322.909 us; speedup vs baseline: 3.0391x; 3.0391x over previous
//
#include <hip/hip_runtime.h>

#define NN 3072
#define FIN 1546
#define KP 1568          // FIN padded to multiple of 32
#define MAXR 192         // max CSR nnz/row (measured mean ~61)

#define XS4_BLOCKS (NN * KP / 1024)        // 4704  (4 elems/thread)
#define WSPLIT_BLOCKS (256 * KP / 256)     // 1568
#define WGA_BLOCKS 384                      // WgaT transpose+split
#define CSR_BLOCKS (NN / 4)                // 768
#define FC1_BLOCKS (NN / 16 * 4)           // 768: 192 row-tiles x 4 col-tiles

typedef __attribute__((ext_vector_type(8))) __bf16 bf16x8;
typedef __attribute__((ext_vector_type(4))) __bf16 bf16x4;
typedef __attribute__((ext_vector_type(4))) float f32x4;

// ---- k1: X split x4 ; Wfc1 split ; WgaT transpose+split ----
__global__ __launch_bounds__(256) void prep1_k(const float* __restrict__ X,
                                               __bf16* __restrict__ Xh, __bf16* __restrict__ Xl,
                                               const float* __restrict__ W,
                                               __bf16* __restrict__ WhT, __bf16* __restrict__ WlT,
                                               const float* __restrict__ Wga0,
                                               const float* __restrict__ Wga1,
                                               const float* __restrict__ Wga2,
                                               __bf16* __restrict__ WgaTh, __bf16* __restrict__ WgaTl) {
    int bid = blockIdx.x;
    if (bid < XS4_BLOCKS) {
        int e = (bid * 256 + threadIdx.x) * 4;        // 4 elems, same row (KP%4==0)
        int i = e / KP, c = e - i * KP;
        const float* xr = X + (size_t)i * FIN + c;
        float x0 = (c + 0 < FIN) ? xr[0] : 0.f;
        float x1 = (c + 1 < FIN) ? xr[1] : 0.f;
        float x2 = (c + 2 < FIN) ? xr[2] : 0.f;
        float x3 = (c + 3 < FIN) ? xr[3] : 0.f;
        __bf16 h0 = (__bf16)x0, h1 = (__bf16)x1, h2 = (__bf16)x2, h3 = (__bf16)x3;
        bf16x4 hv = {h0, h1, h2, h3};
        bf16x4 lv = {(__bf16)(x0 - (float)h0), (__bf16)(x1 - (float)h1),
                     (__bf16)(x2 - (float)h2), (__bf16)(x3 - (float)h3)};
        *(bf16x4*)(Xh + e) = hv;
        *(bf16x4*)(Xl + e) = lv;
        return;
    }
    bid -= XS4_BLOCKS;
    if (bid < WSPLIT_BLOCKS) {
        int idx = bid * 256 + threadIdx.x;
        int c = idx / KP, k = idx - c * KP;
        float x = (k < FIN) ? W[(size_t)k * 256 + c] : 0.f;
        __bf16 h = (__bf16)x;
        WhT[idx] = h;
        WlT[idx] = (__bf16)(x - (float)h);
        return;
    }
    bid -= WSPLIT_BLOCKS;
    // WgaT[b][c][k]: [3][128][256]
    int idx = bid * 256 + threadIdx.x;
    int b = idx >> 15, r = idx & 32767;
    int c = r >> 8, k = r & 255;
    const float* Wp = (b == 0) ? Wga0 : (b == 1) ? Wga1 : Wga2;
    float x = Wp[k * 128 + c];                // Wga: [256][128]
    __bf16 h = (__bf16)x;
    WgaTh[idx] = h;
    WgaTl[idx] = (__bf16)(x - (float)h);
}

// ---- k2: fc1 MFMA (16x64 tiles, direct X0 h/l out)  ||  CSR build ----
__global__ __launch_bounds__(256) void fc1csr_k(const float* __restrict__ adj,
                                                int* __restrict__ cols, float* __restrict__ vals,
                                                int* __restrict__ cnt, float* __restrict__ dvec,
                                                const __bf16* __restrict__ Xh,
                                                const __bf16* __restrict__ Xl,
                                                const __bf16* __restrict__ WhT,
                                                const __bf16* __restrict__ WlT,
                                                const float* __restrict__ bias,
                                                __bf16* __restrict__ X0h,
                                                __bf16* __restrict__ X0l) {
    int bid = blockIdx.x, tid = threadIdx.x;
    if (bid < FC1_BLOCKS) {
        // fc1: 16-row x 64-col tile; wave w owns one 16x16 full-K output fragment.
        int rt = bid >> 2;
        int c0 = (bid & 3) * 64;
        int w = tid >> 6, lane = tid & 63;
        int m = lane & 15, q = lane >> 4;
        int r0 = rt * 16;
        int cw = c0 + w * 16;
        const __bf16* xh = Xh + (size_t)(r0 + m) * KP + q * 8;
        const __bf16* xl = Xl + (size_t)(r0 + m) * KP + q * 8;
        const __bf16* bh = WhT + (size_t)(cw + m) * KP + q * 8;
        const __bf16* bl = WlT + (size_t)(cw + m) * KP + q * 8;

        f32x4 acc;
        #pragma unroll
        for (int r = 0; r < 4; r++) acc[r] = 0.f;

        #pragma unroll 7
        for (int ks = 0; ks < KP; ks += 32) {
            bf16x8 ah = *(const bf16x8*)(xh + ks);
            bf16x8 al = *(const bf16x8*)(xl + ks);
            bf16x8 bhv = *(const bf16x8*)(bh + ks);
            bf16x8 blv = *(const bf16x8*)(bl + ks);
            acc = __builtin_amdgcn_mfma_f32_16x16x32_bf16(ah, bhv, acc, 0, 0, 0);
            acc = __builtin_amdgcn_mfma_f32_16x16x32_bf16(ah, blv, acc, 0, 0, 0);
            acc = __builtin_amdgcn_mfma_f32_16x16x32_bf16(al, bhv, acc, 0, 0, 0);
        }
        int col = cw + m;
        float bv = bias[col];
        #pragma unroll
        for (int r = 0; r < 4; r++) {
            int row = r0 + q * 4 + r;
            float s = fmaxf(acc[r] + bv, 0.f);
            __bf16 h = (__bf16)s;
            X0h[(size_t)row * 256 + col] = h;
            X0l[(size_t)row * 256 + col] = (__bf16)(s - (float)h);
        }
        return;
    }
    // CSR build: 4 rows/block, 1 row/wave, float4 + 4x ballot compaction
    int i = (bid - FC1_BLOCKS) * 4 + (tid >> 6);
    int lane = tid & 63;
    const float* row = adj + (size_t)i * NN;
    unsigned long long below = (1ull << lane) - 1ull;
    float s = 0.f; int count = 0;
    int base = i * MAXR;
    for (int c0 = 0; c0 < NN; c0 += 256) {
        float4 a4 = *(const float4*)(row + c0 + lane * 4);
        float a[4] = {a4.x, a4.y, a4.z, a4.w};
        s += a[0] + a[1] + a[2] + a[3];
        unsigned long long bal[4];
        #pragma unroll
        for (int u = 0; u < 4; u++) bal[u] = __ballot(a[u] != 0.f);
        int before = 0;
        #pragma unroll
        for (int u = 0; u < 4; u++) before += __popcll(bal[u] & below);
        int local = 0;
        #pragma unroll
        for (int u = 0; u < 4; u++) {
            if (a[u] != 0.f) {
                int pos = count + before + local;
                if (pos < MAXR) { cols[base + pos] = c0 + lane * 4 + u; vals[base + pos] = a[u]; }
                local++;
            }
        }
        int tot = 0;
        #pragma unroll
        for (int u = 0; u < 4; u++) tot += __popcll(bal[u]);
        count += tot;
    }
    for (int off = 32; off; off >>= 1) s += __shfl_xor(s, off);
    if (lane == 0) {
        cnt[i] = count < MAXR ? count : MAXR;
        dvec[i] = (s > 0.f) ? 1.0f / sqrtf(s) : 0.f;
    }
}

// ---- k3: threshold masks (mode2 first; 8-lane dot subgroups)  ||  gemm1 (X0 @ Wga) ----
__global__ __launch_bounds__(256) void maskg1_k(const int* __restrict__ cols,
                                                const float* __restrict__ vals,
                                                const int* __restrict__ cnt,
                                                const float* __restrict__ dvec,
                                                const float* __restrict__ thrp,
                                                int* __restrict__ mcols,
                                                float* __restrict__ mvals,
                                                int* __restrict__ mcnt,
                                                float* __restrict__ db,
                                                const __bf16* __restrict__ X0h,
                                                const __bf16* __restrict__ X0l,
                                                const __bf16* __restrict__ WgaTh,
                                                const __bf16* __restrict__ WgaTl,
                                                float* __restrict__ XWall) {
    __shared__ float ds[NN];
    __shared__ int lcols[MAXR];
    __shared__ float lvals[MAXR];
    __shared__ int lcnt;
    __shared__ float osum;
    int bid = blockIdx.x, tid = threadIdx.x;

    if (bid >= 3 * NN) {
        // gemm1: XW[b] = X0 @ Wga[b], 64x64 tile, 4 waves, split-bf16 MFMA
        int g = bid - 3 * NN;
        int bx = g % 48, by = (g / 48) & 1, bz = g / 96;
        int w = tid >> 6, lane = tid & 63;
        int m = lane & 15, q = lane >> 4;
        int i0 = bx * 64, c0 = by * 64;
        int rowA = i0 + w * 16 + m;
        const __bf16* ah = X0h + (size_t)rowA * 256 + q * 8;
        const __bf16* al = X0l + (size_t)rowA * 256 + q * 8;
        const __bf16* bh0 = WgaTh + (size_t)bz * 128 * 256 + (size_t)(c0 + m) * 256 + q * 8;
        const __bf16* bl0 = WgaTl + (size_t)bz * 128 * 256 + (size_t)(c0 + m) * 256 + q * 8;

        f32x4 acc[4];
        #pragma unroll
        for (int ct = 0; ct < 4; ct++)
            #pragma unroll
            for (int r = 0; r < 4; r++) acc[ct][r] = 0.f;

        for (int ks = 0; ks < 256; ks += 32) {
            bf16x8 a_h = *(const bf16x8*)(ah + ks);
            bf16x8 a_l = *(const bf16x8*)(al + ks);
            #pragma unroll
            for (int ct = 0; ct < 4; ct++) {
                bf16x8 b_h = *(const bf16x8*)(bh0 + (size_t)ct * 16 * 256 + ks);
                bf16x8 b_l = *(const bf16x8*)(bl0 + (size_t)ct * 16 * 256 + ks);
                acc[ct] = __builtin_amdgcn_mfma_f32_16x16x32_bf16(a_h, b_h, acc[ct], 0, 0, 0);
                acc[ct] = __builtin_amdgcn_mfma_f32_16x16x32_bf16(a_h, b_l, acc[ct], 0, 0, 0);
                acc[ct] = __builtin_amdgcn_mfma_f32_16x16x32_bf16(a_l, b_h, acc[ct], 0, 0, 0);
            }
        }
        float* outp = XWall + (size_t)bz * NN * 128;
        int rowBase = i0 + w * 16 + q * 4;
        #pragma unroll
        for (int ct = 0; ct < 4; ct++) {
            int col = c0 + ct * 16 + m;
            #pragma unroll
            for (int r = 0; r < 4; r++)
                outp[(size_t)(rowBase + r) * 128 + col] = acc[ct][r];
        }
        return;
    }

    int t = bid;
    int mode, i;
    if (t < NN)          { mode = 2; i = t; }          // heavy An^2 first
    else if (t < 2 * NN) { mode = 0; i = t - NN; }
    else                 { mode = 1; i = t - 2 * NN; }

    mcols += (size_t)mode * NN * MAXR;
    mvals += (size_t)mode * NN * MAXR;
    mcnt  += (size_t)mode * NN;
    db    += (size_t)mode * NN;
    int ni = cnt[i], base = i * MAXR;
    float thr = *thrp;
    float di = dvec[i];

    if (mode < 2) {
        if (tid == 0) lcnt = 0;
        __syncthreads();
        float s = 0.f;
        if (tid < ni) {
            int j = cols[base + tid];
            float a = vals[base + tid];
            float m = (mode == 0) ? a : a * di * dvec[j];
            if (m > thr) {
                int p = atomicAdd(&lcnt, 1);
                mcols[base + p] = j;
                mvals[base + p] = a;
                s = a;
            }
        }
        ds[tid] = s; __syncthreads();
        for (int off = 128; off; off >>= 1) {
            if (tid < off) ds[tid] += ds[tid + off];
            __syncthreads();
        }
        if (tid == 0) {
            mcnt[i] = lcnt;
            db[i] = 1.0f / sqrtf(ds[0] + 1.0f);
        }
        return;
    }

    if (tid == 0) { osum = 0.f; lcnt = 0; }
    for (int j = tid; j < NN; j += 256) ds[j] = 0.f;
    __syncthreads();
    for (int t2 = tid; t2 < ni; t2 += 256) {
        int j = cols[base + t2];
        float a = vals[base + t2];
        lcols[t2] = j; lvals[t2] = a;
        ds[j] = a * dvec[j] * dvec[j];
    }
    __syncthreads();
    int lane = tid & 63, wv = tid >> 6;
    int sub = lane & 7, dg = lane >> 3;      // 8-lane subgroup, 8 dots/wave in flight
    for (int o = wv * 8 + dg; o < ni; o += 32) {
        int j = lcols[o];
        int nj = cnt[j], bj = j * MAXR;
        float dot = 0.f;
        for (int t2 = sub; t2 < nj; t2 += 8)
            dot += vals[bj + t2] * ds[cols[bj + t2]];
        #pragma unroll
        for (int off = 4; off; off >>= 1) dot += __shfl_xor(dot, off);
        if (sub == 0 && di * dvec[j] * dot > thr) {
            int p = atomicAdd(&lcnt, 1);
            mcols[base + p] = j;
            mvals[base + p] = lvals[o];
            atomicAdd(&osum, lvals[o]);
        }
    }
    __syncthreads();
    if (tid == 0) {
        mcnt[i] = lcnt;
        db[i] = 1.0f / sqrtf(osum + 1.0f);
    }
}

// ---- SpMM (+ optional fused HW2 = e1 @ Wgb epilogue, exact f32) ----
__global__ __launch_bounds__(256) void spmm3_k(const int* __restrict__ mcols,
                                               const float* __restrict__ mvals,
                                               const int* __restrict__ mcnt,
                                               const float* __restrict__ db,
                                               const float* __restrict__ Xin,   // [3][NN][128]
                                               const float* __restrict__ bias0,
                                               const float* __restrict__ bias1,
                                               const float* __restrict__ bias2,
                                               float* __restrict__ embf, int coff,
                                               const float* __restrict__ Wgb0,  // [128][128] or null
                                               const float* __restrict__ Wgb1,
                                               const float* __restrict__ Wgb2,
                                               float* __restrict__ HW2out) {    // [3][NN][128] or null
    __shared__ float lcoef[MAXR];
    __shared__ int lj[MAXR];
    __shared__ float4 part[8][32];
    __shared__ float e1row[128];
    __shared__ float part2[2][128];
    int i = blockIdx.x, tid = threadIdx.x, b = blockIdx.y;
    mcols += (size_t)b * NN * MAXR;
    mvals += (size_t)b * NN * MAXR;
    mcnt  += (size_t)b * NN;
    db    += (size_t)b * NN;
    const float* Xb = Xin + (size_t)b * NN * 128;
    const float* bias = (b == 0) ? bias0 : (b == 1) ? bias1 : bias2;
    float dbi = db[i];
    int n = mcnt[i], base = i * MAXR;
    if (tid < n) {
        int j = mcols[base + tid];
        lj[tid] = j;
        lcoef[tid] = mvals[base + tid] * dbi * db[j];
    }
    __syncthreads();
    int g = tid >> 5, c4 = (tid & 31) << 2;
    float4 acc = make_float4(0.f, 0.f, 0.f, 0.f);
    float4 acc2 = make_float4(0.f, 0.f, 0.f, 0.f);
    if (g == 0) {
        float4 x = *(const float4*)&Xb[(size_t)i * 128 + c4];
        float d2 = dbi * dbi;
        acc = make_float4(d2 * x.x, d2 * x.y, d2 * x.z, d2 * x.w);
    }
    int t = g;
    for (; t + 8 < n; t += 16) {
        float cf0 = lcoef[t];
        float4 x0 = *(const float4*)&Xb[(size_t)lj[t] * 128 + c4];
        float cf1 = lcoef[t + 8];
        float4 x1 = *(const float4*)&Xb[(size_t)lj[t + 8] * 128 + c4];
        acc.x += cf0 * x0.x; acc.y += cf0 * x0.y; acc.z += cf0 * x0.z; acc.w += cf0 * x0.w;
        acc2.x += cf1 * x1.x; acc2.y += cf1 * x1.y; acc2.z += cf1 * x1.z; acc2.w += cf1 * x1.w;
    }
    if (t < n) {
        float cf = lcoef[t];
        float4 x = *(const float4*)&Xb[(size_t)lj[t] * 128 + c4];
        acc.x += cf * x.x; acc.y += cf * x.y; acc.z += cf * x.z; acc.w += cf * x.w;
    }
    acc.x += acc2.x; acc.y += acc2.y; acc.z += acc2.z; acc.w += acc2.w;
    part[g][tid & 31] = acc;
    __syncthreads();
    if (tid < 32) {
        float4 s = part[0][tid];
        #pragma unroll
        for (int gg = 1; gg < 8; gg++) {
            float4 t4 = part[gg][tid];
            s.x += t4.x; s.y += t4.y; s.z += t4.z; s.w += t4.w;
        }
        int cc = tid << 2;
        float4 bv = *(const float4*)&bias[cc];
        s.x = fmaxf(s.x + bv.x, 0.f); s.y = fmaxf(s.y + bv.y, 0.f);
        s.z = fmaxf(s.z + bv.z, 0.f); s.w = fmaxf(s.w + bv.w, 0.f);
        *(float4*)&embf[((size_t)b * NN + i) * 256 + coff + cc] = s;
        *(float4*)&e1row[cc] = s;
    }
    if (!HW2out) return;
    __syncthreads();
    // fused HW2[b][i][o] = sum_k e1row[k] * Wgb_b[k][o], exact f32
    int o = tid & 127, h = tid >> 7;
    const float* Wg = (b == 0) ? Wgb0 : (b == 1) ? Wgb1 : Wgb2;
    float ha = 0.f;
    int kbase = h * 64;
    const float* wp = Wg + (size_t)kbase * 128 + o;
    #pragma unroll 8
    for (int kk = 0; kk < 64; kk++)
        ha += e1row[kbase + kk] * wp[(size_t)kk * 128];
    part2[h][o] = ha;
    __syncthreads();
    if (tid < 128)
        HW2out[((size_t)b * NN + i) * 128 + tid] = part2[0][tid] + part2[1][tid];
}

// ---- k6: dilated 3x3 conv + fused uv = emb_row @ [Wa_left | Wa_right] (f32) ----
__global__ __launch_bounds__(256) void convuv_k(const float* __restrict__ emb,
                                                const float* __restrict__ ck,
                                                const float* __restrict__ cb,
                                                float* __restrict__ outf,
                                                const float* __restrict__ Wa,   // [512][64]
                                                float* __restrict__ uvp) {      // [NN][128]
    __shared__ float rows[3][3][256];
    __shared__ float embrow[256];
    __shared__ float part2[2][128];
    int n = blockIdx.x, c = threadIdx.x;
    #pragma unroll
    for (int i = 0; i < 3; i++)
        #pragma unroll
        for (int kh = 0; kh < 3; kh++) {
            int nn2 = n + 2 * kh - 2;
            rows[i][kh][c] = (nn2 >= 0 && nn2 < NN) ? emb[((size_t)i * NN + nn2) * 256 + c] : 0.f;
        }
    __syncthreads();
    float s = cb[0];
    #pragma unroll
    for (int i = 0; i < 3; i++)
        #pragma unroll
        for (int kh = 0; kh < 3; kh++)
            #pragma unroll
            for (int kw = 0; kw < 3; kw++) {
                int cc = c + 2 * kw - 2;
                if (cc >= 0 && cc < 256)
                    s += rows[i][kh][cc] * ck[(i * 3 + kh) * 3 + kw];
            }
    size_t idx = (size_t)n * 256 + c;
    outf[idx] = s;
    embrow[c] = s;
    __syncthreads();
    // uv[n][o] = sum_k emb[n][k] * (o<64 ? Wa[k][o] : Wa[256+k][o-64]), exact f32
    int o = c & 127, h = c >> 7;
    int kbase = h * 128;
    const float* wp = (o < 64) ? (Wa + (size_t)kbase * 64 + o)
                               : (Wa + (size_t)(256 + kbase) * 64 + (o - 64));
    float acc = 0.f;
    #pragma unroll 8
    for (int kk = 0; kk < 128; kk++)
        acc += embrow[kbase + kk] * wp[(size_t)kk * 64];
    part2[h][o] = acc;
    __syncthreads();
    if (c < 128)
        uvp[(size_t)n * 128 + c] = part2[0][c] + part2[1][c];
}

// ---- k7: pair gather + logits: 16 pairs/block, 4 per wave ----
__global__ __launch_bounds__(256) void pairuv_k(const int* __restrict__ left,
                                                const int* __restrict__ right,
                                                const float* __restrict__ uvp,
                                                const float* __restrict__ ba,
                                                const float* __restrict__ Wb,
                                                const float* __restrict__ bb,
                                                float* __restrict__ out) {
    int tid = threadIdx.x;
    int w = tid >> 6, c = tid & 63;
    int base = blockIdx.x * 16 + w * 4;
    float bac = ba[c];
    float w0 = Wb[c * 2], w1 = Wb[c * 2 + 1];
    float b0 = bb[0], b1 = bb[1];
    #pragma unroll
    for (int pp = 0; pp < 4; pp++) {
        int row = base + pp;
        int l = left[row], r = right[row];
        float h = uvp[(size_t)l * 128 + c] + uvp[(size_t)r * 128 + 64 + c] + bac;
        h = fmaxf(h, 0.f);
        float s0 = h * w0, s1 = h * w1;
        for (int off = 32; off; off >>= 1) {
            s0 += __shfl_xor(s0, off);
            s1 += __shfl_xor(s1, off);
        }
        if (c == 0) {
            out[row * 2]     = s0 + b0;
            out[row * 2 + 1] = s1 + b1;
        }
    }
}

extern "C" void kernel_launch(void* const* d_in, const int* in_sizes, int n_in,
                              void* d_out, int out_size, void* d_ws, size_t ws_size,
                              hipStream_t stream) {
    const int* left  = (const int*)d_in[0];
    const int* right = (const int*)d_in[1];
    const float* X    = (const float*)d_in[2];
    const float* adj  = (const float*)d_in[3];
    const float* thr  = (const float*)d_in[4];
    const float* Wfc1 = (const float*)d_in[5];
    const float* bfc1 = (const float*)d_in[6];
    // channel order b0,b1,b2 = (adj mask, Wg5/6), (An mask, Wg3/4), (An^2 mask, Wg1/2)
    const float* Wga[3] = { (const float*)d_in[15], (const float*)d_in[11], (const float*)d_in[7] };
    const float* bga[3] = { (const float*)d_in[16], (const float*)d_in[12], (const float*)d_in[8] };
    const float* Wgb[3] = { (const float*)d_in[17], (const float*)d_in[13], (const float*)d_in[9] };
    const float* bgb[3] = { (const float*)d_in[18], (const float*)d_in[14], (const float*)d_in[10] };
    const float* cnnk = (const float*)d_in[19];
    const float* cnnb = (const float*)d_in[20];
    const float* Wa_  = (const float*)d_in[21];
    const float* ba_  = (const float*)d_in[22];
    const float* Wb_  = (const float*)d_in[23];
    const float* bb_  = (const float*)d_in[24];

    char* p = (char*)d_ws;
    auto take = [&](size_t n) { char* q = p; p += (n + 255) & ~(size_t)255; return q; };
    float* dvec = (float*)take(NN * 4);
    float* db3  = (float*)take((size_t)3 * NN * 4);
    int*   cnt  = (int*)take(NN * 4);
    int*   mcnt3 = (int*)take((size_t)3 * NN * 4);
    int*   cols = (int*)take((size_t)NN * MAXR * 4);
    float* vals = (float*)take((size_t)NN * MAXR * 4);
    int*   mcols3 = (int*)take((size_t)3 * NN * MAXR * 4);    // 7.1 MB
    float* mvals3 = (float*)take((size_t)3 * NN * MAXR * 4);  // 7.1 MB
    __bf16* X0h  = (__bf16*)take((size_t)NN * 256 * 2);
    __bf16* X0l  = (__bf16*)take((size_t)NN * 256 * 2);
    float* XWall = (float*)take((size_t)3 * NN * 128 * 4);
    float* HW2all= (float*)take((size_t)3 * NN * 128 * 4);
    float* embf  = (float*)take((size_t)3 * NN * 256 * 4);
    __bf16* Xh   = (__bf16*)take((size_t)NN * KP * 2);        // 9.6 MB
    __bf16* Xl   = (__bf16*)take((size_t)NN * KP * 2);        // 9.6 MB
    __bf16* WhT  = (__bf16*)take((size_t)256 * KP * 2);       // 0.8 MB
    __bf16* WlT  = (__bf16*)take((size_t)256 * KP * 2);       // 0.8 MB
    __bf16* WgaTh = (__bf16*)take((size_t)3 * 128 * 256 * 2);
    __bf16* WgaTl = (__bf16*)take((size_t)3 * 128 * 256 * 2);
    float* uvp   = (float*)take((size_t)NN * 128 * 4);        // 1.5 MB

    float* out_logits = (float*)d_out;
    float* out_emb = out_logits + 32768;

    // k1: X split + Wfc1 split + WgaT transpose-split
    prep1_k<<<XS4_BLOCKS + WSPLIT_BLOCKS + WGA_BLOCKS, 256, 0, stream>>>(
        X, Xh, Xl, Wfc1, WhT, WlT, Wga[0], Wga[1], Wga[2], WgaTh, WgaTl);

    // k2: fc1 (needs k1)  ||  CSR build (needs only adj)
    fc1csr_k<<<FC1_BLOCKS + CSR_BLOCKS, 256, 0, stream>>>(
        adj, cols, vals, cnt, dvec, Xh, Xl, WhT, WlT, bfc1, X0h, X0l);

    // k3: masks (need CSR)  ||  gemm1 XW = X0 @ Wga (needs X0)
    maskg1_k<<<3 * NN + 288, 256, 0, stream>>>(cols, vals, cnt, dvec, thr,
                                               mcols3, mvals3, mcnt3, db3,
                                               X0h, X0l, WgaTh, WgaTl, XWall);

    // k4: e1 = relu(An @ XW + bga) -> embf[0..127]  +  fused HW2 = e1 @ Wgb
    spmm3_k<<<dim3(NN, 3), 256, 0, stream>>>(mcols3, mvals3, mcnt3, db3, XWall,
                                             bga[0], bga[1], bga[2], embf, 0,
                                             Wgb[0], Wgb[1], Wgb[2], HW2all);

    // k5: e2 = relu(An @ HW2 + bgb) -> embf[128..255]
    spmm3_k<<<dim3(NN, 3), 256, 0, stream>>>(mcols3, mvals3, mcnt3, db3, HW2all,
                                             bgb[0], bgb[1], bgb[2], embf, 128,
                                             (const float*)0, (const float*)0, (const float*)0,
                                             (float*)0);

    // k6: dilated conv -> out_emb + fused uv = emb @ [Wa_l | Wa_r]
    convuv_k<<<NN, 256, 0, stream>>>(embf, cnnk, cnnb, out_emb, Wa_, uvp);

    // k7: pair gather + logits
    pairuv_k<<<16384 / 16, 256, 0, stream>>>(left, right, uvp, ba_, Wb_, bb_, out_logits);
}

// Round 6
// 305.351 us; speedup vs baseline: 3.2139x; 1.0575x over previous
//
#include <hip/hip_runtime.h>

#define NN 3072
#define FIN 1546
#define KP 1568          // FIN padded to multiple of 32 (weights only)
#define MAXR 192         // max CSR nnz/row (measured mean ~61)
#define KSPLIT 7
#define KSLICE 224       // 7*224 = 1568

#define WSPLIT_BLOCKS (256 * KP / 256)     // 1568
#define WGA_BLOCKS 384                      // WgaT transpose+split
#define CSR_BLOCKS (NN / 4)                // 768
#define FC1_BLOCKS (48 * 4 * KSPLIT)       // 1344 split-K tiles
#define RED_BLOCKS 768                      // split-K reduce: 1 float4/thread

typedef __attribute__((ext_vector_type(8))) __bf16 bf16x8;
typedef __attribute__((ext_vector_type(4))) __bf16 bf16x4;
typedef __attribute__((ext_vector_type(4))) float f32x4;

// ---- k1: Wfc1 split ; WgaT transpose+split ; CSR build (prefetched) ----
__global__ __launch_bounds__(256) void prep_k(const float* __restrict__ adj,
                                              int* __restrict__ cols, float* __restrict__ vals,
                                              int* __restrict__ cnt, float* __restrict__ dvec,
                                              const float* __restrict__ W,
                                              __bf16* __restrict__ WhT, __bf16* __restrict__ WlT,
                                              const float* __restrict__ Wga0,
                                              const float* __restrict__ Wga1,
                                              const float* __restrict__ Wga2,
                                              __bf16* __restrict__ WgaTh, __bf16* __restrict__ WgaTl) {
    int bid = blockIdx.x;
    if (bid < WSPLIT_BLOCKS) {
        int idx = bid * 256 + threadIdx.x;
        int c = idx / KP, k = idx - c * KP;
        float x = (k < FIN) ? W[(size_t)k * 256 + c] : 0.f;
        __bf16 h = (__bf16)x;
        WhT[idx] = h;
        WlT[idx] = (__bf16)(x - (float)h);
        return;
    }
    bid -= WSPLIT_BLOCKS;
    if (bid < WGA_BLOCKS) {
        // WgaT[b][c][k]: [3][128][256]
        int idx = bid * 256 + threadIdx.x;
        int b = idx >> 15, r = idx & 32767;
        int c = r >> 8, k = r & 255;
        const float* Wp = (b == 0) ? Wga0 : (b == 1) ? Wga1 : Wga2;
        float x = Wp[k * 128 + c];            // Wga: [256][128]
        __bf16 h = (__bf16)x;
        WgaTh[idx] = h;
        WgaTl[idx] = (__bf16)(x - (float)h);
        return;
    }
    bid -= WGA_BLOCKS;
    // CSR build: 4 rows/block, 1 row/wave, float4 + 4x ballot compaction, 2-deep prefetch
    int i = bid * 4 + (threadIdx.x >> 6);
    int lane = threadIdx.x & 63;
    const float* row = adj + (size_t)i * NN;
    unsigned long long below = (1ull << lane) - 1ull;
    float s = 0.f; int count = 0;
    int base = i * MAXR;
    float4 a4 = *(const float4*)(row + lane * 4);
    for (int c0 = 0; c0 < NN; c0 += 256) {
        float4 nxt;
        if (c0 + 256 < NN) nxt = *(const float4*)(row + c0 + 256 + lane * 4);
        float a[4] = {a4.x, a4.y, a4.z, a4.w};
        s += a[0] + a[1] + a[2] + a[3];
        unsigned long long bal[4];
        #pragma unroll
        for (int u = 0; u < 4; u++) bal[u] = __ballot(a[u] != 0.f);
        int before = 0;
        #pragma unroll
        for (int u = 0; u < 4; u++) before += __popcll(bal[u] & below);
        int local = 0;
        #pragma unroll
        for (int u = 0; u < 4; u++) {
            if (a[u] != 0.f) {
                int pos = count + before + local;
                if (pos < MAXR) { cols[base + pos] = c0 + lane * 4 + u; vals[base + pos] = a[u]; }
                local++;
            }
        }
        int tot = 0;
        #pragma unroll
        for (int u = 0; u < 4; u++) tot += __popcll(bal[u]);
        count += tot;
        a4 = nxt;
    }
    for (int off = 32; off; off >>= 1) s += __shfl_xor(s, off);
    if (lane == 0) {
        cnt[i] = count < MAXR ? count : MAXR;
        dvec[i] = (s > 0.f) ? 1.0f / sqrtf(s) : 0.f;
    }
}

// ---- k2: fc1 split-K MFMA (A = X f32, in-register h/l split)  ||  masks mode0/1 ----
__global__ __launch_bounds__(256) void fc1mask01_k(const float* __restrict__ X,
                                                   const __bf16* __restrict__ WhT,
                                                   const __bf16* __restrict__ WlT,
                                                   float* __restrict__ Cpart,
                                                   const int* __restrict__ cols,
                                                   const float* __restrict__ vals,
                                                   const int* __restrict__ cnt,
                                                   const float* __restrict__ dvec,
                                                   const float* __restrict__ thrp,
                                                   int* __restrict__ mcols,
                                                   float* __restrict__ mvals,
                                                   int* __restrict__ mcnt,
                                                   float* __restrict__ db) {
    __shared__ float ds[256];
    __shared__ int lcnt;
    int bid = blockIdx.x, tid = threadIdx.x;

    if (bid < FC1_BLOCKS) {
        // split-K fc1: 64x64 tile, 4 waves, K-slice z of 224
        int bx = bid % 48;
        int byz = bid / 48;
        int by = byz % 4, z = byz / 4;
        int w = tid >> 6, lane = tid & 63;
        int m = lane & 15, q = lane >> 4;
        int i0 = bx * 64, c0 = by * 64;
        int k0 = z * KSLICE;
        int rowA = i0 + w * 16 + m;
        const float* xrow = X + (size_t)rowA * FIN + k0 + q * 8;
        const __bf16* bh0 = WhT + (size_t)(c0 + m) * KP + k0 + q * 8;
        const __bf16* bl0 = WlT + (size_t)(c0 + m) * KP + k0 + q * 8;

        f32x4 acc[4];
        #pragma unroll
        for (int ct = 0; ct < 4; ct++)
            #pragma unroll
            for (int r = 0; r < 4; r++) acc[ct][r] = 0.f;

        #pragma unroll 2
        for (int ks = 0; ks < KSLICE; ks += 32) {
            float xv[8];
            if (z < KSPLIT - 1) {
                // fast path: all k < FIN; 8B-aligned float2 loads (X rows are 8B-aligned)
                const float2* xp = (const float2*)(xrow + ks);
                float2 p0 = xp[0], p1 = xp[1], p2 = xp[2], p3 = xp[3];
                xv[0] = p0.x; xv[1] = p0.y; xv[2] = p1.x; xv[3] = p1.y;
                xv[4] = p2.x; xv[5] = p2.y; xv[6] = p3.x; xv[7] = p3.y;
            } else {
                int kb = k0 + q * 8 + ks;
                #pragma unroll
                for (int e = 0; e < 8; e++)
                    xv[e] = (kb + e < FIN) ? xrow[ks + e] : 0.f;
            }
            bf16x8 ah, al;
            #pragma unroll
            for (int e = 0; e < 8; e++) {
                __bf16 h = (__bf16)xv[e];
                ah[e] = h;
                al[e] = (__bf16)(xv[e] - (float)h);
            }
            #pragma unroll
            for (int ct = 0; ct < 4; ct++) {
                bf16x8 bh = *(const bf16x8*)(bh0 + (size_t)ct * 16 * KP + ks);
                bf16x8 bl = *(const bf16x8*)(bl0 + (size_t)ct * 16 * KP + ks);
                acc[ct] = __builtin_amdgcn_mfma_f32_16x16x32_bf16(ah, bh, acc[ct], 0, 0, 0);
                acc[ct] = __builtin_amdgcn_mfma_f32_16x16x32_bf16(ah, bl, acc[ct], 0, 0, 0);
                acc[ct] = __builtin_amdgcn_mfma_f32_16x16x32_bf16(al, bh, acc[ct], 0, 0, 0);
            }
        }
        float* outp = Cpart + (size_t)z * NN * 256;
        int rowBase = i0 + w * 16 + q * 4;
        #pragma unroll
        for (int ct = 0; ct < 4; ct++) {
            int col = c0 + ct * 16 + m;
            #pragma unroll
            for (int r = 0; r < 4; r++)
                outp[(size_t)(rowBase + r) * 256 + col] = acc[ct][r];
        }
        return;
    }

    // light masks: mode 0 (adj) and mode 1 (An)
    int t = bid - FC1_BLOCKS;
    int mode = (t < NN) ? 0 : 1;
    int i = (t < NN) ? t : t - NN;

    mcols += (size_t)mode * NN * MAXR;
    mvals += (size_t)mode * NN * MAXR;
    mcnt  += (size_t)mode * NN;
    db    += (size_t)mode * NN;
    int ni = cnt[i], base = i * MAXR;
    float thr = *thrp;
    float di = dvec[i];

    if (tid == 0) lcnt = 0;
    __syncthreads();
    float s = 0.f;
    if (tid < ni) {
        int j = cols[base + tid];
        float a = vals[base + tid];
        float mv = (mode == 0) ? a : a * di * dvec[j];
        if (mv > thr) {
            int p = atomicAdd(&lcnt, 1);
            mcols[base + p] = j;
            mvals[base + p] = a;
            s = a;
        }
    }
    ds[tid] = s; __syncthreads();
    for (int off = 128; off; off >>= 1) {
        if (tid < off) ds[tid] += ds[tid + off];
        __syncthreads();
    }
    if (tid == 0) {
        mcnt[i] = lcnt;
        db[i] = 1.0f / sqrtf(ds[0] + 1.0f);
    }
}

// ---- k3: split-K reduce -> X0 h/l  ||  mode2 An^2 mask (8-lane dot subgroups) ----
__global__ __launch_bounds__(256) void redm2_k(const float* __restrict__ Cpart,
                                               const float* __restrict__ bias,
                                               __bf16* __restrict__ X0h,
                                               __bf16* __restrict__ X0l,
                                               const int* __restrict__ cols,
                                               const float* __restrict__ vals,
                                               const int* __restrict__ cnt,
                                               const float* __restrict__ dvec,
                                               const float* __restrict__ thrp,
                                               int* __restrict__ mcols,
                                               float* __restrict__ mvals,
                                               int* __restrict__ mcnt,
                                               float* __restrict__ db) {
    __shared__ float ds[NN];
    __shared__ int lcols[MAXR];
    __shared__ float lvals[MAXR];
    __shared__ int lcnt;
    __shared__ float osum;
    int bid = blockIdx.x, tid = threadIdx.x;

    if (bid < RED_BLOCKS) {
        // reduce: one float4 per thread over 7 planes + bias + relu -> h/l
        int idx4 = bid * 256 + tid;
        int i = idx4 >> 6, c4 = (idx4 & 63) << 2;
        float4 s = ((const float4*)Cpart)[idx4];
        #pragma unroll
        for (int z = 1; z < KSPLIT; z++) {
            float4 t4 = ((const float4*)(Cpart + (size_t)z * NN * 256))[idx4];
            s.x += t4.x; s.y += t4.y; s.z += t4.z; s.w += t4.w;
        }
        float4 b = *(const float4*)&bias[c4];
        s.x = fmaxf(s.x + b.x, 0.f); s.y = fmaxf(s.y + b.y, 0.f);
        s.z = fmaxf(s.z + b.z, 0.f); s.w = fmaxf(s.w + b.w, 0.f);
        __bf16 h0 = (__bf16)s.x, h1 = (__bf16)s.y, h2 = (__bf16)s.z, h3 = (__bf16)s.w;
        bf16x4 hv = {h0, h1, h2, h3};
        bf16x4 lv = {(__bf16)(s.x - (float)h0), (__bf16)(s.y - (float)h1),
                     (__bf16)(s.z - (float)h2), (__bf16)(s.w - (float)h3)};
        *(bf16x4*)(X0h + (size_t)i * 256 + c4) = hv;
        *(bf16x4*)(X0l + (size_t)i * 256 + c4) = lv;
        return;
    }

    // mode2: An^2 sparse x sparse threshold mask
    int i = bid - RED_BLOCKS;
    mcols += (size_t)2 * NN * MAXR;
    mvals += (size_t)2 * NN * MAXR;
    mcnt  += (size_t)2 * NN;
    db    += (size_t)2 * NN;
    int ni = cnt[i], base = i * MAXR;
    float thr = *thrp;
    float di = dvec[i];

    if (tid == 0) { osum = 0.f; lcnt = 0; }
    for (int j = tid; j < NN; j += 256) ds[j] = 0.f;
    __syncthreads();
    for (int t2 = tid; t2 < ni; t2 += 256) {
        int j = cols[base + t2];
        float a = vals[base + t2];
        lcols[t2] = j; lvals[t2] = a;
        ds[j] = a * dvec[j] * dvec[j];
    }
    __syncthreads();
    int lane = tid & 63, wv = tid >> 6;
    int sub = lane & 7, dg = lane >> 3;      // 8-lane subgroup, 8 dots/wave in flight
    for (int o = wv * 8 + dg; o < ni; o += 32) {
        int j = lcols[o];
        int nj = cnt[j], bj = j * MAXR;
        float dot = 0.f;
        for (int t2 = sub; t2 < nj; t2 += 8)
            dot += vals[bj + t2] * ds[cols[bj + t2]];
        #pragma unroll
        for (int off = 4; off; off >>= 1) dot += __shfl_xor(dot, off);
        if (sub == 0 && di * dvec[j] * dot > thr) {
            int p = atomicAdd(&lcnt, 1);
            mcols[base + p] = j;
            mvals[base + p] = lvals[o];
            atomicAdd(&osum, lvals[o]);
        }
    }
    __syncthreads();
    if (tid == 0) {
        mcnt[i] = lcnt;
        db[i] = 1.0f / sqrtf(osum + 1.0f);
    }
}

// ---- k4: gemm1 XW[b] = X0 @ Wga[b] (MFMA split-bf16, 64x64 tile) ----
__global__ __launch_bounds__(256) void gemm1_k(const __bf16* __restrict__ X0h,
                                               const __bf16* __restrict__ X0l,
                                               const __bf16* __restrict__ WgaTh,
                                               const __bf16* __restrict__ WgaTl,
                                               float* __restrict__ XWall) {
    int tid = threadIdx.x;
    int w = tid >> 6, lane = tid & 63;
    int m = lane & 15, q = lane >> 4;
    int i0 = blockIdx.x * 64, c0 = blockIdx.y * 64;
    int bz = blockIdx.z;
    int rowA = i0 + w * 16 + m;
    const __bf16* ah = X0h + (size_t)rowA * 256 + q * 8;
    const __bf16* al = X0l + (size_t)rowA * 256 + q * 8;
    const __bf16* bh0 = WgaTh + (size_t)bz * 128 * 256 + (size_t)(c0 + m) * 256 + q * 8;
    const __bf16* bl0 = WgaTl + (size_t)bz * 128 * 256 + (size_t)(c0 + m) * 256 + q * 8;

    f32x4 acc[4];
    #pragma unroll
    for (int ct = 0; ct < 4; ct++)
        #pragma unroll
        for (int r = 0; r < 4; r++) acc[ct][r] = 0.f;

    for (int ks = 0; ks < 256; ks += 32) {
        bf16x8 a_h = *(const bf16x8*)(ah + ks);
        bf16x8 a_l = *(const bf16x8*)(al + ks);
        #pragma unroll
        for (int ct = 0; ct < 4; ct++) {
            bf16x8 b_h = *(const bf16x8*)(bh0 + (size_t)ct * 16 * 256 + ks);
            bf16x8 b_l = *(const bf16x8*)(bl0 + (size_t)ct * 16 * 256 + ks);
            acc[ct] = __builtin_amdgcn_mfma_f32_16x16x32_bf16(a_h, b_h, acc[ct], 0, 0, 0);
            acc[ct] = __builtin_amdgcn_mfma_f32_16x16x32_bf16(a_h, b_l, acc[ct], 0, 0, 0);
            acc[ct] = __builtin_amdgcn_mfma_f32_16x16x32_bf16(a_l, b_h, acc[ct], 0, 0, 0);
        }
    }
    float* outp = XWall + (size_t)bz * NN * 128;
    int rowBase = i0 + w * 16 + q * 4;
    #pragma unroll
    for (int ct = 0; ct < 4; ct++) {
        int col = c0 + ct * 16 + m;
        #pragma unroll
        for (int r = 0; r < 4; r++)
            outp[(size_t)(rowBase + r) * 128 + col] = acc[ct][r];
    }
}

// ---- SpMM (+ optional fused HW2 = e1 @ Wgb epilogue, exact f32) ----
__global__ __launch_bounds__(256) void spmm3_k(const int* __restrict__ mcols,
                                               const float* __restrict__ mvals,
                                               const int* __restrict__ mcnt,
                                               const float* __restrict__ db,
                                               const float* __restrict__ Xin,   // [3][NN][128]
                                               const float* __restrict__ bias0,
                                               const float* __restrict__ bias1,
                                               const float* __restrict__ bias2,
                                               float* __restrict__ embf, int coff,
                                               const float* __restrict__ Wgb0,  // [128][128] or null
                                               const float* __restrict__ Wgb1,
                                               const float* __restrict__ Wgb2,
                                               float* __restrict__ HW2out) {    // [3][NN][128] or null
    __shared__ float lcoef[MAXR];
    __shared__ int lj[MAXR];
    __shared__ float4 part[8][32];
    __shared__ float e1row[128];
    __shared__ float part2[2][128];
    int i = blockIdx.x, tid = threadIdx.x, b = blockIdx.y;
    mcols += (size_t)b * NN * MAXR;
    mvals += (size_t)b * NN * MAXR;
    mcnt  += (size_t)b * NN;
    db    += (size_t)b * NN;
    const float* Xb = Xin + (size_t)b * NN * 128;
    const float* bias = (b == 0) ? bias0 : (b == 1) ? bias1 : bias2;
    float dbi = db[i];
    int n = mcnt[i], base = i * MAXR;
    if (tid < n) {
        int j = mcols[base + tid];
        lj[tid] = j;
        lcoef[tid] = mvals[base + tid] * dbi * db[j];
    }
    __syncthreads();
    int g = tid >> 5, c4 = (tid & 31) << 2;
    float4 acc = make_float4(0.f, 0.f, 0.f, 0.f);
    float4 acc2 = make_float4(0.f, 0.f, 0.f, 0.f);
    if (g == 0) {
        float4 x = *(const float4*)&Xb[(size_t)i * 128 + c4];
        float d2 = dbi * dbi;
        acc = make_float4(d2 * x.x, d2 * x.y, d2 * x.z, d2 * x.w);
    }
    int t = g;
    for (; t + 8 < n; t += 16) {
        float cf0 = lcoef[t];
        float4 x0 = *(const float4*)&Xb[(size_t)lj[t] * 128 + c4];
        float cf1 = lcoef[t + 8];
        float4 x1 = *(const float4*)&Xb[(size_t)lj[t + 8] * 128 + c4];
        acc.x += cf0 * x0.x; acc.y += cf0 * x0.y; acc.z += cf0 * x0.z; acc.w += cf0 * x0.w;
        acc2.x += cf1 * x1.x; acc2.y += cf1 * x1.y; acc2.z += cf1 * x1.z; acc2.w += cf1 * x1.w;
    }
    if (t < n) {
        float cf = lcoef[t];
        float4 x = *(const float4*)&Xb[(size_t)lj[t] * 128 + c4];
        acc.x += cf * x.x; acc.y += cf * x.y; acc.z += cf * x.z; acc.w += cf * x.w;
    }
    acc.x += acc2.x; acc.y += acc2.y; acc.z += acc2.z; acc.w += acc2.w;
    part[g][tid & 31] = acc;
    __syncthreads();
    if (tid < 32) {
        float4 s = part[0][tid];
        #pragma unroll
        for (int gg = 1; gg < 8; gg++) {
            float4 t4 = part[gg][tid];
            s.x += t4.x; s.y += t4.y; s.z += t4.z; s.w += t4.w;
        }
        int cc = tid << 2;
        float4 bv = *(const float4*)&bias[cc];
        s.x = fmaxf(s.x + bv.x, 0.f); s.y = fmaxf(s.y + bv.y, 0.f);
        s.z = fmaxf(s.z + bv.z, 0.f); s.w = fmaxf(s.w + bv.w, 0.f);
        *(float4*)&embf[((size_t)b * NN + i) * 256 + coff + cc] = s;
        *(float4*)&e1row[cc] = s;
    }
    if (!HW2out) return;
    __syncthreads();
    // fused HW2[b][i][o] = sum_k e1row[k] * Wgb_b[k][o], exact f32
    int o = tid & 127, h = tid >> 7;
    const float* Wg = (b == 0) ? Wgb0 : (b == 1) ? Wgb1 : Wgb2;
    float ha = 0.f;
    int kbase = h * 64;
    const float* wp = Wg + (size_t)kbase * 128 + o;
    #pragma unroll 8
    for (int kk = 0; kk < 64; kk++)
        ha += e1row[kbase + kk] * wp[(size_t)kk * 128];
    part2[h][o] = ha;
    __syncthreads();
    if (tid < 128)
        HW2out[((size_t)b * NN + i) * 128 + tid] = part2[0][tid] + part2[1][tid];
}

// ---- k7: dilated 3x3 conv + fused uv = emb_row @ [Wa_left | Wa_right] (f32) ----
__global__ __launch_bounds__(256) void convuv_k(const float* __restrict__ emb,
                                                const float* __restrict__ ck,
                                                const float* __restrict__ cb,
                                                float* __restrict__ outf,
                                                const float* __restrict__ Wa,   // [512][64]
                                                float* __restrict__ uvp) {      // [NN][128]
    __shared__ float rows[3][3][256];
    __shared__ float embrow[256];
    __shared__ float part2[2][128];
    int n = blockIdx.x, c = threadIdx.x;
    #pragma unroll
    for (int i = 0; i < 3; i++)
        #pragma unroll
        for (int kh = 0; kh < 3; kh++) {
            int nn2 = n + 2 * kh - 2;
            rows[i][kh][c] = (nn2 >= 0 && nn2 < NN) ? emb[((size_t)i * NN + nn2) * 256 + c] : 0.f;
        }
    __syncthreads();
    float s = cb[0];
    #pragma unroll
    for (int i = 0; i < 3; i++)
        #pragma unroll
        for (int kh = 0; kh < 3; kh++)
            #pragma unroll
            for (int kw = 0; kw < 3; kw++) {
                int cc = c + 2 * kw - 2;
                if (cc >= 0 && cc < 256)
                    s += rows[i][kh][cc] * ck[(i * 3 + kh) * 3 + kw];
            }
    size_t idx = (size_t)n * 256 + c;
    outf[idx] = s;
    embrow[c] = s;
    __syncthreads();
    // uv[n][o] = sum_k emb[n][k] * (o<64 ? Wa[k][o] : Wa[256+k][o-64]), exact f32
    int o = c & 127, h = c >> 7;
    int kbase = h * 128;
    const float* wp = (o < 64) ? (Wa + (size_t)kbase * 64 + o)
                               : (Wa + (size_t)(256 + kbase) * 64 + (o - 64));
    float acc = 0.f;
    #pragma unroll 8
    for (int kk = 0; kk < 128; kk++)
        acc += embrow[kbase + kk] * wp[(size_t)kk * 64];
    part2[h][o] = acc;
    __syncthreads();
    if (c < 128)
        uvp[(size_t)n * 128 + c] = part2[0][c] + part2[1][c];
}

// ---- k8: pair gather + logits: 16 pairs/block, 4 per wave ----
__global__ __launch_bounds__(256) void pairuv_k(const int* __restrict__ left,
                                                const int* __restrict__ right,
                                                const float* __restrict__ uvp,
                                                const float* __restrict__ ba,
                                                const float* __restrict__ Wb,
                                                const float* __restrict__ bb,
                                                float* __restrict__ out) {
    int tid = threadIdx.x;
    int w = tid >> 6, c = tid & 63;
    int base = blockIdx.x * 16 + w * 4;
    float bac = ba[c];
    float w0 = Wb[c * 2], w1 = Wb[c * 2 + 1];
    float b0 = bb[0], b1 = bb[1];
    #pragma unroll
    for (int pp = 0; pp < 4; pp++) {
        int row = base + pp;
        int l = left[row], r = right[row];
        float h = uvp[(size_t)l * 128 + c] + uvp[(size_t)r * 128 + 64 + c] + bac;
        h = fmaxf(h, 0.f);
        float s0 = h * w0, s1 = h * w1;
        for (int off = 32; off; off >>= 1) {
            s0 += __shfl_xor(s0, off);
            s1 += __shfl_xor(s1, off);
        }
        if (c == 0) {
            out[row * 2]     = s0 + b0;
            out[row * 2 + 1] = s1 + b1;
        }
    }
}

extern "C" void kernel_launch(void* const* d_in, const int* in_sizes, int n_in,
                              void* d_out, int out_size, void* d_ws, size_t ws_size,
                              hipStream_t stream) {
    const int* left  = (const int*)d_in[0];
    const int* right = (const int*)d_in[1];
    const float* X    = (const float*)d_in[2];
    const float* adj  = (const float*)d_in[3];
    const float* thr  = (const float*)d_in[4];
    const float* Wfc1 = (const float*)d_in[5];
    const float* bfc1 = (const float*)d_in[6];
    // channel order b0,b1,b2 = (adj mask, Wg5/6), (An mask, Wg3/4), (An^2 mask, Wg1/2)
    const float* Wga[3] = { (const float*)d_in[15], (const float*)d_in[11], (const float*)d_in[7] };
    const float* bga[3] = { (const float*)d_in[16], (const float*)d_in[12], (const float*)d_in[8] };
    const float* Wgb[3] = { (const float*)d_in[17], (const float*)d_in[13], (const float*)d_in[9] };
    const float* bgb[3] = { (const float*)d_in[18], (const float*)d_in[14], (const float*)d_in[10] };
    const float* cnnk = (const float*)d_in[19];
    const float* cnnb = (const float*)d_in[20];
    const float* Wa_  = (const float*)d_in[21];
    const float* ba_  = (const float*)d_in[22];
    const float* Wb_  = (const float*)d_in[23];
    const float* bb_  = (const float*)d_in[24];

    char* p = (char*)d_ws;
    auto take = [&](size_t n) { char* q = p; p += (n + 255) & ~(size_t)255; return q; };
    float* dvec = (float*)take(NN * 4);
    float* db3  = (float*)take((size_t)3 * NN * 4);
    int*   cnt  = (int*)take(NN * 4);
    int*   mcnt3 = (int*)take((size_t)3 * NN * 4);
    int*   cols = (int*)take((size_t)NN * MAXR * 4);
    float* vals = (float*)take((size_t)NN * MAXR * 4);
    int*   mcols3 = (int*)take((size_t)3 * NN * MAXR * 4);    // 7.1 MB
    float* mvals3 = (float*)take((size_t)3 * NN * MAXR * 4);  // 7.1 MB
    float* Cpart = (float*)take((size_t)KSPLIT * NN * 256 * 4); // 22.0 MB
    __bf16* X0h  = (__bf16*)take((size_t)NN * 256 * 2);
    __bf16* X0l  = (__bf16*)take((size_t)NN * 256 * 2);
    float* XWall = (float*)take((size_t)3 * NN * 128 * 4);
    float* HW2all= (float*)take((size_t)3 * NN * 128 * 4);
    float* embf  = (float*)take((size_t)3 * NN * 256 * 4);
    __bf16* WhT  = (__bf16*)take((size_t)256 * KP * 2);       // 0.8 MB
    __bf16* WlT  = (__bf16*)take((size_t)256 * KP * 2);       // 0.8 MB
    __bf16* WgaTh = (__bf16*)take((size_t)3 * 128 * 256 * 2);
    __bf16* WgaTl = (__bf16*)take((size_t)3 * 128 * 256 * 2);
    float* uvp   = (float*)take((size_t)NN * 128 * 4);        // 1.5 MB

    float* out_logits = (float*)d_out;
    float* out_emb = out_logits + 32768;

    // k1: Wfc1 split + WgaT split + CSR build (all independent)
    prep_k<<<WSPLIT_BLOCKS + WGA_BLOCKS + CSR_BLOCKS, 256, 0, stream>>>(
        adj, cols, vals, cnt, dvec, Wfc1, WhT, WlT,
        Wga[0], Wga[1], Wga[2], WgaTh, WgaTl);

    // k2: fc1 split-K (X direct, 1344 blocks)  ||  masks mode0/1 (need CSR)
    fc1mask01_k<<<FC1_BLOCKS + 2 * NN, 256, 0, stream>>>(
        X, WhT, WlT, Cpart,
        cols, vals, cnt, dvec, thr, mcols3, mvals3, mcnt3, db3);

    // k3: split-K reduce -> X0 h/l  ||  mode2 An^2 mask
    redm2_k<<<RED_BLOCKS + NN, 256, 0, stream>>>(
        Cpart, bfc1, X0h, X0l,
        cols, vals, cnt, dvec, thr, mcols3, mvals3, mcnt3, db3);

    // k4: gemm1 XW = X0 @ Wga
    gemm1_k<<<dim3(NN / 64, 2, 3), 256, 0, stream>>>(X0h, X0l, WgaTh, WgaTl, XWall);

    // k5: e1 = relu(An @ XW + bga) -> embf[0..127]  +  fused HW2 = e1 @ Wgb
    spmm3_k<<<dim3(NN, 3), 256, 0, stream>>>(mcols3, mvals3, mcnt3, db3, XWall,
                                             bga[0], bga[1], bga[2], embf, 0,
                                             Wgb[0], Wgb[1], Wgb[2], HW2all);

    // k6: e2 = relu(An @ HW2 + bgb) -> embf[128..255]
    spmm3_k<<<dim3(NN, 3), 256, 0, stream>>>(mcols3, mvals3, mcnt3, db3, HW2all,
                                             bgb[0], bgb[1], bgb[2], embf, 128,
                                             (const float*)0, (const float*)0, (const float*)0,
                                             (float*)0);

    // k7: dilated conv -> out_emb + fused uv = emb @ [Wa_l | Wa_r]
    convuv_k<<<NN, 256, 0, stream>>>(embf, cnnk, cnnb, out_emb, Wa_, uvp);

    // k8: pair gather + logits
    pairuv_k<<<16384 / 16, 256, 0, stream>>>(left, right, uvp, ba_, Wb_, bb_, out_logits);
}

// Round 7
// 302.767 us; speedup vs baseline: 3.2413x; 1.0085x over previous
//
#include <hip/hip_runtime.h>

#define NN 3072
#define FIN 1546
#define KP 1568          // FIN padded to multiple of 32 (weights only)
#define MAXR 192         // max CSR nnz/row (measured mean ~61)
#define KSPLIT 7
#define KSLICE 224       // 7*224 = 1568

#define WSPLIT_BLOCKS (256 * KP / 256)     // 1568
#define WGA_BLOCKS 384                      // WgaT transpose+split
#define CSR_BLOCKS (NN / 4)                // 768
#define FC1_BLOCKS (48 * 4 * KSPLIT)       // 1344 split-K tiles
#define RED_BLOCKS 768                      // split-K reduce: 1 float4/thread

typedef __attribute__((ext_vector_type(8))) __bf16 bf16x8;
typedef __attribute__((ext_vector_type(4))) __bf16 bf16x4;
typedef __attribute__((ext_vector_type(4))) float f32x4;

// ---- k1: Wfc1 split ; WgaT transpose+split ; CSR build (prefetched) ----
__global__ __launch_bounds__(256) void prep_k(const float* __restrict__ adj,
                                              int* __restrict__ cols, float* __restrict__ vals,
                                              int* __restrict__ cnt, float* __restrict__ dvec,
                                              const float* __restrict__ W,
                                              __bf16* __restrict__ WhT, __bf16* __restrict__ WlT,
                                              const float* __restrict__ Wga0,
                                              const float* __restrict__ Wga1,
                                              const float* __restrict__ Wga2,
                                              __bf16* __restrict__ WgaTh, __bf16* __restrict__ WgaTl) {
    int bid = blockIdx.x;
    if (bid < WSPLIT_BLOCKS) {
        int idx = bid * 256 + threadIdx.x;
        int c = idx / KP, k = idx - c * KP;
        float x = (k < FIN) ? W[(size_t)k * 256 + c] : 0.f;
        __bf16 h = (__bf16)x;
        WhT[idx] = h;
        WlT[idx] = (__bf16)(x - (float)h);
        return;
    }
    bid -= WSPLIT_BLOCKS;
    if (bid < WGA_BLOCKS) {
        // WgaT[b][c][k]: [3][128][256]
        int idx = bid * 256 + threadIdx.x;
        int b = idx >> 15, r = idx & 32767;
        int c = r >> 8, k = r & 255;
        const float* Wp = (b == 0) ? Wga0 : (b == 1) ? Wga1 : Wga2;
        float x = Wp[k * 128 + c];            // Wga: [256][128]
        __bf16 h = (__bf16)x;
        WgaTh[idx] = h;
        WgaTl[idx] = (__bf16)(x - (float)h);
        return;
    }
    bid -= WGA_BLOCKS;
    // CSR build: 4 rows/block, 1 row/wave, float4 + 4x ballot compaction, 2-deep prefetch
    int i = bid * 4 + (threadIdx.x >> 6);
    int lane = threadIdx.x & 63;
    const float* row = adj + (size_t)i * NN;
    unsigned long long below = (1ull << lane) - 1ull;
    float s = 0.f; int count = 0;
    int base = i * MAXR;
    float4 a4 = *(const float4*)(row + lane * 4);
    for (int c0 = 0; c0 < NN; c0 += 256) {
        float4 nxt;
        if (c0 + 256 < NN) nxt = *(const float4*)(row + c0 + 256 + lane * 4);
        float a[4] = {a4.x, a4.y, a4.z, a4.w};
        s += a[0] + a[1] + a[2] + a[3];
        unsigned long long bal[4];
        #pragma unroll
        for (int u = 0; u < 4; u++) bal[u] = __ballot(a[u] != 0.f);
        int before = 0;
        #pragma unroll
        for (int u = 0; u < 4; u++) before += __popcll(bal[u] & below);
        int local = 0;
        #pragma unroll
        for (int u = 0; u < 4; u++) {
            if (a[u] != 0.f) {
                int pos = count + before + local;
                if (pos < MAXR) { cols[base + pos] = c0 + lane * 4 + u; vals[base + pos] = a[u]; }
                local++;
            }
        }
        int tot = 0;
        #pragma unroll
        for (int u = 0; u < 4; u++) tot += __popcll(bal[u]);
        count += tot;
        a4 = nxt;
    }
    for (int off = 32; off; off >>= 1) s += __shfl_xor(s, off);
    if (lane == 0) {
        cnt[i] = count < MAXR ? count : MAXR;
        dvec[i] = (s > 0.f) ? 1.0f / sqrtf(s) : 0.f;
    }
}

// ---- k2: fc1 split-K MFMA (A = X f32, in-register h/l)  ||  ALL masks (2,0,1) ----
// block order: [0,FC1) fc1; [+NN) mode2 heavy An^2; [+NN) mode0; [+NN) mode1.
__global__ __launch_bounds__(256) void fc1maskall_k(const float* __restrict__ X,
                                                    const __bf16* __restrict__ WhT,
                                                    const __bf16* __restrict__ WlT,
                                                    float* __restrict__ Cpart,
                                                    const int* __restrict__ cols,
                                                    const float* __restrict__ vals,
                                                    const int* __restrict__ cnt,
                                                    const float* __restrict__ dvec,
                                                    const float* __restrict__ thrp,
                                                    int* __restrict__ mcols,
                                                    float* __restrict__ mvals,
                                                    int* __restrict__ mcnt,
                                                    float* __restrict__ db) {
    __shared__ float ds[NN];
    __shared__ int lcols[MAXR];
    __shared__ float lvals[MAXR];
    __shared__ int lcnt;
    __shared__ float osum;
    int bid = blockIdx.x, tid = threadIdx.x;

    if (bid < FC1_BLOCKS) {
        // split-K fc1: 64x64 tile, 4 waves, K-slice z of 224
        int bx = bid % 48;
        int byz = bid / 48;
        int by = byz % 4, z = byz / 4;
        int w = tid >> 6, lane = tid & 63;
        int m = lane & 15, q = lane >> 4;
        int i0 = bx * 64, c0 = by * 64;
        int k0 = z * KSLICE;
        int rowA = i0 + w * 16 + m;
        const float* xrow = X + (size_t)rowA * FIN + k0 + q * 8;
        const __bf16* bh0 = WhT + (size_t)(c0 + m) * KP + k0 + q * 8;
        const __bf16* bl0 = WlT + (size_t)(c0 + m) * KP + k0 + q * 8;

        f32x4 acc[4];
        #pragma unroll
        for (int ct = 0; ct < 4; ct++)
            #pragma unroll
            for (int r = 0; r < 4; r++) acc[ct][r] = 0.f;

        #pragma unroll 2
        for (int ks = 0; ks < KSLICE; ks += 32) {
            float xv[8];
            if (z < KSPLIT - 1) {
                // fast path: all k < FIN; 8B-aligned float2 loads (X rows are 8B-aligned)
                const float2* xp = (const float2*)(xrow + ks);
                float2 p0 = xp[0], p1 = xp[1], p2 = xp[2], p3 = xp[3];
                xv[0] = p0.x; xv[1] = p0.y; xv[2] = p1.x; xv[3] = p1.y;
                xv[4] = p2.x; xv[5] = p2.y; xv[6] = p3.x; xv[7] = p3.y;
            } else {
                int kb = k0 + q * 8 + ks;
                #pragma unroll
                for (int e = 0; e < 8; e++)
                    xv[e] = (kb + e < FIN) ? xrow[ks + e] : 0.f;
            }
            bf16x8 ah, al;
            #pragma unroll
            for (int e = 0; e < 8; e++) {
                __bf16 h = (__bf16)xv[e];
                ah[e] = h;
                al[e] = (__bf16)(xv[e] - (float)h);
            }
            #pragma unroll
            for (int ct = 0; ct < 4; ct++) {
                bf16x8 bh = *(const bf16x8*)(bh0 + (size_t)ct * 16 * KP + ks);
                bf16x8 bl = *(const bf16x8*)(bl0 + (size_t)ct * 16 * KP + ks);
                acc[ct] = __builtin_amdgcn_mfma_f32_16x16x32_bf16(ah, bh, acc[ct], 0, 0, 0);
                acc[ct] = __builtin_amdgcn_mfma_f32_16x16x32_bf16(ah, bl, acc[ct], 0, 0, 0);
                acc[ct] = __builtin_amdgcn_mfma_f32_16x16x32_bf16(al, bh, acc[ct], 0, 0, 0);
            }
        }
        float* outp = Cpart + (size_t)z * NN * 256;
        int rowBase = i0 + w * 16 + q * 4;
        #pragma unroll
        for (int ct = 0; ct < 4; ct++) {
            int col = c0 + ct * 16 + m;
            #pragma unroll
            for (int r = 0; r < 4; r++)
                outp[(size_t)(rowBase + r) * 256 + col] = acc[ct][r];
        }
        return;
    }

    int t = bid - FC1_BLOCKS;
    float thr = *thrp;

    if (t < NN) {
        // mode2: An^2 sparse x sparse threshold mask (vectorized int4/float4 gather)
        int i = t;
        mcols += (size_t)2 * NN * MAXR;
        mvals += (size_t)2 * NN * MAXR;
        mcnt  += (size_t)2 * NN;
        db    += (size_t)2 * NN;
        int ni = cnt[i], base = i * MAXR;
        float di = dvec[i];

        if (tid == 0) { osum = 0.f; lcnt = 0; }
        for (int j = tid; j < NN; j += 256) ds[j] = 0.f;
        __syncthreads();
        for (int t2 = tid; t2 < ni; t2 += 256) {
            int j = cols[base + t2];
            float a = vals[base + t2];
            lcols[t2] = j; lvals[t2] = a;
            ds[j] = a * dvec[j] * dvec[j];
        }
        __syncthreads();
        int lane = tid & 63, wv = tid >> 6;
        int sub = lane & 7, dg = lane >> 3;      // 8-lane subgroup, 8 dots/wave in flight
        for (int o = wv * 8 + dg; o < ni; o += 32) {
            int j = lcols[o];
            int nj = cnt[j], bj = j * MAXR;
            float dot = 0.f;
            int nv = nj & ~3;
            for (int t2 = sub * 4; t2 < nv; t2 += 32) {
                int4 c4 = *(const int4*)&cols[bj + t2];
                float4 v4 = *(const float4*)&vals[bj + t2];
                dot += v4.x * ds[c4.x] + v4.y * ds[c4.y]
                     + v4.z * ds[c4.z] + v4.w * ds[c4.w];
            }
            if (sub == 0)
                for (int t2 = nv; t2 < nj; t2++)
                    dot += vals[bj + t2] * ds[cols[bj + t2]];
            #pragma unroll
            for (int off = 4; off; off >>= 1) dot += __shfl_xor(dot, off);
            if (sub == 0 && di * dvec[j] * dot > thr) {
                int p = atomicAdd(&lcnt, 1);
                mcols[base + p] = j;
                mvals[base + p] = lvals[o];
                atomicAdd(&osum, lvals[o]);
            }
        }
        __syncthreads();
        if (tid == 0) {
            mcnt[i] = lcnt;
            db[i] = 1.0f / sqrtf(osum + 1.0f);
        }
        return;
    }

    // light masks: mode 0 (adj) and mode 1 (An)
    t -= NN;
    int mode = (t < NN) ? 0 : 1;
    int i = (t < NN) ? t : t - NN;

    mcols += (size_t)mode * NN * MAXR;
    mvals += (size_t)mode * NN * MAXR;
    mcnt  += (size_t)mode * NN;
    db    += (size_t)mode * NN;
    int ni = cnt[i], base = i * MAXR;
    float di = dvec[i];

    if (tid == 0) lcnt = 0;
    __syncthreads();
    float s = 0.f;
    if (tid < ni) {
        int j = cols[base + tid];
        float a = vals[base + tid];
        float mv = (mode == 0) ? a : a * di * dvec[j];
        if (mv > thr) {
            int p = atomicAdd(&lcnt, 1);
            mcols[base + p] = j;
            mvals[base + p] = a;
            s = a;
        }
    }
    ds[tid] = s; __syncthreads();
    for (int off = 128; off; off >>= 1) {
        if (tid < off) ds[tid] += ds[tid + off];
        __syncthreads();
    }
    if (tid == 0) {
        mcnt[i] = lcnt;
        db[i] = 1.0f / sqrtf(ds[0] + 1.0f);
    }
}

// ---- k3: split-K reduce -> X0 h/l (768 blocks, BW-bound) ----
__global__ __launch_bounds__(256) void red_k(const float* __restrict__ Cpart,
                                             const float* __restrict__ bias,
                                             __bf16* __restrict__ X0h,
                                             __bf16* __restrict__ X0l) {
    int idx4 = blockIdx.x * 256 + threadIdx.x;
    int i = idx4 >> 6, c4 = (idx4 & 63) << 2;
    float4 s = ((const float4*)Cpart)[idx4];
    #pragma unroll
    for (int z = 1; z < KSPLIT; z++) {
        float4 t4 = ((const float4*)(Cpart + (size_t)z * NN * 256))[idx4];
        s.x += t4.x; s.y += t4.y; s.z += t4.z; s.w += t4.w;
    }
    float4 b = *(const float4*)&bias[c4];
    s.x = fmaxf(s.x + b.x, 0.f); s.y = fmaxf(s.y + b.y, 0.f);
    s.z = fmaxf(s.z + b.z, 0.f); s.w = fmaxf(s.w + b.w, 0.f);
    __bf16 h0 = (__bf16)s.x, h1 = (__bf16)s.y, h2 = (__bf16)s.z, h3 = (__bf16)s.w;
    bf16x4 hv = {h0, h1, h2, h3};
    bf16x4 lv = {(__bf16)(s.x - (float)h0), (__bf16)(s.y - (float)h1),
                 (__bf16)(s.z - (float)h2), (__bf16)(s.w - (float)h3)};
    *(bf16x4*)(X0h + (size_t)i * 256 + c4) = hv;
    *(bf16x4*)(X0l + (size_t)i * 256 + c4) = lv;
}

// ---- k4: gemm1 XW[b] = X0 @ Wga[b] (MFMA split-bf16, 64x64 tile) ----
__global__ __launch_bounds__(256) void gemm1_k(const __bf16* __restrict__ X0h,
                                               const __bf16* __restrict__ X0l,
                                               const __bf16* __restrict__ WgaTh,
                                               const __bf16* __restrict__ WgaTl,
                                               float* __restrict__ XWall) {
    int tid = threadIdx.x;
    int w = tid >> 6, lane = tid & 63;
    int m = lane & 15, q = lane >> 4;
    int i0 = blockIdx.x * 64, c0 = blockIdx.y * 64;
    int bz = blockIdx.z;
    int rowA = i0 + w * 16 + m;
    const __bf16* ah = X0h + (size_t)rowA * 256 + q * 8;
    const __bf16* al = X0l + (size_t)rowA * 256 + q * 8;
    const __bf16* bh0 = WgaTh + (size_t)bz * 128 * 256 + (size_t)(c0 + m) * 256 + q * 8;
    const __bf16* bl0 = WgaTl + (size_t)bz * 128 * 256 + (size_t)(c0 + m) * 256 + q * 8;

    f32x4 acc[4];
    #pragma unroll
    for (int ct = 0; ct < 4; ct++)
        #pragma unroll
        for (int r = 0; r < 4; r++) acc[ct][r] = 0.f;

    for (int ks = 0; ks < 256; ks += 32) {
        bf16x8 a_h = *(const bf16x8*)(ah + ks);
        bf16x8 a_l = *(const bf16x8*)(al + ks);
        #pragma unroll
        for (int ct = 0; ct < 4; ct++) {
            bf16x8 b_h = *(const bf16x8*)(bh0 + (size_t)ct * 16 * 256 + ks);
            bf16x8 b_l = *(const bf16x8*)(bl0 + (size_t)ct * 16 * 256 + ks);
            acc[ct] = __builtin_amdgcn_mfma_f32_16x16x32_bf16(a_h, b_h, acc[ct], 0, 0, 0);
            acc[ct] = __builtin_amdgcn_mfma_f32_16x16x32_bf16(a_h, b_l, acc[ct], 0, 0, 0);
            acc[ct] = __builtin_amdgcn_mfma_f32_16x16x32_bf16(a_l, b_h, acc[ct], 0, 0, 0);
        }
    }
    float* outp = XWall + (size_t)bz * NN * 128;
    int rowBase = i0 + w * 16 + q * 4;
    #pragma unroll
    for (int ct = 0; ct < 4; ct++) {
        int col = c0 + ct * 16 + m;
        #pragma unroll
        for (int r = 0; r < 4; r++)
            outp[(size_t)(rowBase + r) * 128 + col] = acc[ct][r];
    }
}

// ---- SpMM (+ optional fused HW2 = e1 @ Wgb epilogue, exact f32) ----
__global__ __launch_bounds__(256) void spmm3_k(const int* __restrict__ mcols,
                                               const float* __restrict__ mvals,
                                               const int* __restrict__ mcnt,
                                               const float* __restrict__ db,
                                               const float* __restrict__ Xin,   // [3][NN][128]
                                               const float* __restrict__ bias0,
                                               const float* __restrict__ bias1,
                                               const float* __restrict__ bias2,
                                               float* __restrict__ embf, int coff,
                                               const float* __restrict__ Wgb0,  // [128][128] or null
                                               const float* __restrict__ Wgb1,
                                               const float* __restrict__ Wgb2,
                                               float* __restrict__ HW2out) {    // [3][NN][128] or null
    __shared__ float lcoef[MAXR];
    __shared__ int lj[MAXR];
    __shared__ float4 part[8][32];
    __shared__ float e1row[128];
    __shared__ float part2[2][128];
    int i = blockIdx.x, tid = threadIdx.x, b = blockIdx.y;
    mcols += (size_t)b * NN * MAXR;
    mvals += (size_t)b * NN * MAXR;
    mcnt  += (size_t)b * NN;
    db    += (size_t)b * NN;
    const float* Xb = Xin + (size_t)b * NN * 128;
    const float* bias = (b == 0) ? bias0 : (b == 1) ? bias1 : bias2;
    float dbi = db[i];
    int n = mcnt[i], base = i * MAXR;
    if (tid < n) {
        int j = mcols[base + tid];
        lj[tid] = j;
        lcoef[tid] = mvals[base + tid] * dbi * db[j];
    }
    __syncthreads();
    int g = tid >> 5, c4 = (tid & 31) << 2;
    float4 acc = make_float4(0.f, 0.f, 0.f, 0.f);
    float4 acc2 = make_float4(0.f, 0.f, 0.f, 0.f);
    if (g == 0) {
        float4 x = *(const float4*)&Xb[(size_t)i * 128 + c4];
        float d2 = dbi * dbi;
        acc = make_float4(d2 * x.x, d2 * x.y, d2 * x.z, d2 * x.w);
    }
    int t = g;
    for (; t + 8 < n; t += 16) {
        float cf0 = lcoef[t];
        float4 x0 = *(const float4*)&Xb[(size_t)lj[t] * 128 + c4];
        float cf1 = lcoef[t + 8];
        float4 x1 = *(const float4*)&Xb[(size_t)lj[t + 8] * 128 + c4];
        acc.x += cf0 * x0.x; acc.y += cf0 * x0.y; acc.z += cf0 * x0.z; acc.w += cf0 * x0.w;
        acc2.x += cf1 * x1.x; acc2.y += cf1 * x1.y; acc2.z += cf1 * x1.z; acc2.w += cf1 * x1.w;
    }
    if (t < n) {
        float cf = lcoef[t];
        float4 x = *(const float4*)&Xb[(size_t)lj[t] * 128 + c4];
        acc.x += cf * x.x; acc.y += cf * x.y; acc.z += cf * x.z; acc.w += cf * x.w;
    }
    acc.x += acc2.x; acc.y += acc2.y; acc.z += acc2.z; acc.w += acc2.w;
    part[g][tid & 31] = acc;
    __syncthreads();
    if (tid < 32) {
        float4 s = part[0][tid];
        #pragma unroll
        for (int gg = 1; gg < 8; gg++) {
            float4 t4 = part[gg][tid];
            s.x += t4.x; s.y += t4.y; s.z += t4.z; s.w += t4.w;
        }
        int cc = tid << 2;
        float4 bv = *(const float4*)&bias[cc];
        s.x = fmaxf(s.x + bv.x, 0.f); s.y = fmaxf(s.y + bv.y, 0.f);
        s.z = fmaxf(s.z + bv.z, 0.f); s.w = fmaxf(s.w + bv.w, 0.f);
        *(float4*)&embf[((size_t)b * NN + i) * 256 + coff + cc] = s;
        *(float4*)&e1row[cc] = s;
    }
    if (!HW2out) return;
    __syncthreads();
    // fused HW2[b][i][o] = sum_k e1row[k] * Wgb_b[k][o], exact f32
    int o = tid & 127, h = tid >> 7;
    const float* Wg = (b == 0) ? Wgb0 : (b == 1) ? Wgb1 : Wgb2;
    float ha = 0.f;
    int kbase = h * 64;
    const float* wp = Wg + (size_t)kbase * 128 + o;
    #pragma unroll 8
    for (int kk = 0; kk < 64; kk++)
        ha += e1row[kbase + kk] * wp[(size_t)kk * 128];
    part2[h][o] = ha;
    __syncthreads();
    if (tid < 128)
        HW2out[((size_t)b * NN + i) * 128 + tid] = part2[0][tid] + part2[1][tid];
}

// ---- k7: dilated 3x3 conv + fused uv = emb_row @ [Wa_left | Wa_right] (f32) ----
__global__ __launch_bounds__(256) void convuv_k(const float* __restrict__ emb,
                                                const float* __restrict__ ck,
                                                const float* __restrict__ cb,
                                                float* __restrict__ outf,
                                                const float* __restrict__ Wa,   // [512][64]
                                                float* __restrict__ uvp) {      // [NN][128]
    __shared__ float rows[3][3][256];
    __shared__ float embrow[256];
    __shared__ float part2[2][128];
    int n = blockIdx.x, c = threadIdx.x;
    #pragma unroll
    for (int i = 0; i < 3; i++)
        #pragma unroll
        for (int kh = 0; kh < 3; kh++) {
            int nn2 = n + 2 * kh - 2;
            rows[i][kh][c] = (nn2 >= 0 && nn2 < NN) ? emb[((size_t)i * NN + nn2) * 256 + c] : 0.f;
        }
    __syncthreads();
    float s = cb[0];
    #pragma unroll
    for (int i = 0; i < 3; i++)
        #pragma unroll
        for (int kh = 0; kh < 3; kh++)
            #pragma unroll
            for (int kw = 0; kw < 3; kw++) {
                int cc = c + 2 * kw - 2;
                if (cc >= 0 && cc < 256)
                    s += rows[i][kh][cc] * ck[(i * 3 + kh) * 3 + kw];
            }
    size_t idx = (size_t)n * 256 + c;
    outf[idx] = s;
    embrow[c] = s;
    __syncthreads();
    // uv[n][o] = sum_k emb[n][k] * (o<64 ? Wa[k][o] : Wa[256+k][o-64]), exact f32
    int o = c & 127, h = c >> 7;
    int kbase = h * 128;
    const float* wp = (o < 64) ? (Wa + (size_t)kbase * 64 + o)
                               : (Wa + (size_t)(256 + kbase) * 64 + (o - 64));
    float acc = 0.f;
    #pragma unroll 8
    for (int kk = 0; kk < 128; kk++)
        acc += embrow[kbase + kk] * wp[(size_t)kk * 64];
    part2[h][o] = acc;
    __syncthreads();
    if (c < 128)
        uvp[(size_t)n * 128 + c] = part2[0][c] + part2[1][c];
}

// ---- k8: pair gather + logits: 16 pairs/block, 4 per wave ----
__global__ __launch_bounds__(256) void pairuv_k(const int* __restrict__ left,
                                                const int* __restrict__ right,
                                                const float* __restrict__ uvp,
                                                const float* __restrict__ ba,
                                                const float* __restrict__ Wb,
                                                const float* __restrict__ bb,
                                                float* __restrict__ out) {
    int tid = threadIdx.x;
    int w = tid >> 6, c = tid & 63;
    int base = blockIdx.x * 16 + w * 4;
    float bac = ba[c];
    float w0 = Wb[c * 2], w1 = Wb[c * 2 + 1];
    float b0 = bb[0], b1 = bb[1];
    #pragma unroll
    for (int pp = 0; pp < 4; pp++) {
        int row = base + pp;
        int l = left[row], r = right[row];
        float h = uvp[(size_t)l * 128 + c] + uvp[(size_t)r * 128 + 64 + c] + bac;
        h = fmaxf(h, 0.f);
        float s0 = h * w0, s1 = h * w1;
        for (int off = 32; off; off >>= 1) {
            s0 += __shfl_xor(s0, off);
            s1 += __shfl_xor(s1, off);
        }
        if (c == 0) {
            out[row * 2]     = s0 + b0;
            out[row * 2 + 1] = s1 + b1;
        }
    }
}

extern "C" void kernel_launch(void* const* d_in, const int* in_sizes, int n_in,
                              void* d_out, int out_size, void* d_ws, size_t ws_size,
                              hipStream_t stream) {
    const int* left  = (const int*)d_in[0];
    const int* right = (const int*)d_in[1];
    const float* X    = (const float*)d_in[2];
    const float* adj  = (const float*)d_in[3];
    const float* thr  = (const float*)d_in[4];
    const float* Wfc1 = (const float*)d_in[5];
    const float* bfc1 = (const float*)d_in[6];
    // channel order b0,b1,b2 = (adj mask, Wg5/6), (An mask, Wg3/4), (An^2 mask, Wg1/2)
    const float* Wga[3] = { (const float*)d_in[15], (const float*)d_in[11], (const float*)d_in[7] };
    const float* bga[3] = { (const float*)d_in[16], (const float*)d_in[12], (const float*)d_in[8] };
    const float* Wgb[3] = { (const float*)d_in[17], (const float*)d_in[13], (const float*)d_in[9] };
    const float* bgb[3] = { (const float*)d_in[18], (const float*)d_in[14], (const float*)d_in[10] };
    const float* cnnk = (const float*)d_in[19];
    const float* cnnb = (const float*)d_in[20];
    const float* Wa_  = (const float*)d_in[21];
    const float* ba_  = (const float*)d_in[22];
    const float* Wb_  = (const float*)d_in[23];
    const float* bb_  = (const float*)d_in[24];

    char* p = (char*)d_ws;
    auto take = [&](size_t n) { char* q = p; p += (n + 255) & ~(size_t)255; return q; };
    float* dvec = (float*)take(NN * 4);
    float* db3  = (float*)take((size_t)3 * NN * 4);
    int*   cnt  = (int*)take(NN * 4);
    int*   mcnt3 = (int*)take((size_t)3 * NN * 4);
    int*   cols = (int*)take((size_t)NN * MAXR * 4);
    float* vals = (float*)take((size_t)NN * MAXR * 4);
    int*   mcols3 = (int*)take((size_t)3 * NN * MAXR * 4);    // 7.1 MB
    float* mvals3 = (float*)take((size_t)3 * NN * MAXR * 4);  // 7.1 MB
    float* Cpart = (float*)take((size_t)KSPLIT * NN * 256 * 4); // 22.0 MB
    __bf16* X0h  = (__bf16*)take((size_t)NN * 256 * 2);
    __bf16* X0l  = (__bf16*)take((size_t)NN * 256 * 2);
    float* XWall = (float*)take((size_t)3 * NN * 128 * 4);
    float* HW2all= (float*)take((size_t)3 * NN * 128 * 4);
    float* embf  = (float*)take((size_t)3 * NN * 256 * 4);
    __bf16* WhT  = (__bf16*)take((size_t)256 * KP * 2);       // 0.8 MB
    __bf16* WlT  = (__bf16*)take((size_t)256 * KP * 2);       // 0.8 MB
    __bf16* WgaTh = (__bf16*)take((size_t)3 * 128 * 256 * 2);
    __bf16* WgaTl = (__bf16*)take((size_t)3 * 128 * 256 * 2);
    float* uvp   = (float*)take((size_t)NN * 128 * 4);        // 1.5 MB

    float* out_logits = (float*)d_out;
    float* out_emb = out_logits + 32768;

    // k1: Wfc1 split + WgaT split + CSR build (all independent)
    prep_k<<<WSPLIT_BLOCKS + WGA_BLOCKS + CSR_BLOCKS, 256, 0, stream>>>(
        adj, cols, vals, cnt, dvec, Wfc1, WhT, WlT,
        Wga[0], Wga[1], Wga[2], WgaTh, WgaTl);

    // k2: fc1 split-K (X direct)  ||  ALL masks (mode2 + mode0/1) — one wide dispatch
    fc1maskall_k<<<FC1_BLOCKS + 3 * NN, 256, 0, stream>>>(
        X, WhT, WlT, Cpart,
        cols, vals, cnt, dvec, thr, mcols3, mvals3, mcnt3, db3);

    // k3: split-K reduce -> X0 h/l (BW-bound, ~7 us)
    red_k<<<RED_BLOCKS, 256, 0, stream>>>(Cpart, bfc1, X0h, X0l);

    // k4: gemm1 XW = X0 @ Wga
    gemm1_k<<<dim3(NN / 64, 2, 3), 256, 0, stream>>>(X0h, X0l, WgaTh, WgaTl, XWall);

    // k5: e1 = relu(An @ XW + bga) -> embf[0..127]  +  fused HW2 = e1 @ Wgb
    spmm3_k<<<dim3(NN, 3), 256, 0, stream>>>(mcols3, mvals3, mcnt3, db3, XWall,
                                             bga[0], bga[1], bga[2], embf, 0,
                                             Wgb[0], Wgb[1], Wgb[2], HW2all);

    // k6: e2 = relu(An @ HW2 + bgb) -> embf[128..255]
    spmm3_k<<<dim3(NN, 3), 256, 0, stream>>>(mcols3, mvals3, mcnt3, db3, HW2all,
                                             bgb[0], bgb[1], bgb[2], embf, 128,
                                             (const float*)0, (const float*)0, (const float*)0,
                                             (float*)0);

    // k7: dilated conv -> out_emb + fused uv = emb @ [Wa_l | Wa_r]
    convuv_k<<<NN, 256, 0, stream>>>(embf, cnnk, cnnb, out_emb, Wa_, uvp);

    // k8: pair gather + logits
    pairuv_k<<<16384 / 16, 256, 0, stream>>>(left, right, uvp, ba_, Wb_, bb_, out_logits);
}